// Round 1
// baseline (2824.485 us; speedup 1.0000x reference)
//
#include <hip/hip_runtime.h>

#define NUSERS 100000
#define NITEMS 50000
#define NN (NUSERS + NITEMS)      // 150000
#define NE 4000000
#define DIM 64
#define BQ 4096
#define KHOPS 3

// ---------------- kernels ----------------

__global__ void k_degree(const int* __restrict__ row, float* __restrict__ deg, int E) {
    int i = blockIdx.x * blockDim.x + threadIdx.x;
    if (i < E) unsafeAtomicAdd(&deg[row[i]], 1.0f);
}

__global__ void k_inv_sqrt(float* __restrict__ deg, int N) {
    int i = blockIdx.x * blockDim.x + threadIdx.x;
    if (i < N) {
        float d = deg[i];
        deg[i] = (d > 0.0f) ? (1.0f / sqrtf(d)) : 0.0f;
    }
}

__global__ void k_weights(const int* __restrict__ row, const int* __restrict__ col,
                          const float* __restrict__ dis, float* __restrict__ w, int E) {
    int i = blockIdx.x * blockDim.x + threadIdx.x;
    if (i < E) w[i] = dis[row[i]] * dis[col[i]];
}

__global__ void k_concat(const float* __restrict__ u, const float* __restrict__ it,
                         float* __restrict__ emb) {
    int i = blockIdx.x * blockDim.x + threadIdx.x;
    const int NU = NUSERS * DIM;
    const int NT = NN * DIM;
    if (i < NU) emb[i] = u[i];
    else if (i < NT) emb[i] = it[i - NU];
}

// One wave (64 lanes) per edge; lane == dim. Coalesced 256B read of emb[col],
// coalesced 256B atomic-add burst into out[row].
__global__ void k_spmm(const int* __restrict__ row, const int* __restrict__ col,
                       const float* __restrict__ w, const float* __restrict__ in,
                       float* __restrict__ out, int E) {
    int lane = threadIdx.x & 63;
    int wid  = (blockIdx.x * blockDim.x + threadIdx.x) >> 6;
    int nw   = (gridDim.x * blockDim.x) >> 6;
    for (int e = wid; e < E; e += nw) {
        int r = row[e];
        int c = col[e];
        float we = w[e];
        float v = we * in[c * DIM + lane];
        unsafeAtomicAdd(&out[r * DIM + lane], v);
    }
}

// out[b, 0:64]   = emb[user_id[b]]
// out[b, 64:128] = emb[NUSERS + item_ids[b]]
__global__ void k_gather_init(const int* __restrict__ uid, const int* __restrict__ iid,
                              const float* __restrict__ emb, float* __restrict__ out) {
    int t = blockIdx.x * blockDim.x + threadIdx.x;   // 0 .. BQ*DIM-1
    if (t >= BQ * DIM) return;
    int b = t >> 6;
    int d = t & 63;
    out[b * (2 * DIM) + d]       = emb[uid[b] * DIM + d];
    out[b * (2 * DIM) + DIM + d] = emb[(NUSERS + iid[b]) * DIM + d];
}

__global__ void k_gather_add(const int* __restrict__ uid, const int* __restrict__ iid,
                             const float* __restrict__ emb, float* __restrict__ out,
                             float scale) {
    int t = blockIdx.x * blockDim.x + threadIdx.x;
    if (t >= BQ * DIM) return;
    int b = t >> 6;
    int d = t & 63;
    int ou = b * (2 * DIM) + d;
    int oi = ou + DIM;
    out[ou] = (out[ou] + emb[uid[b] * DIM + d]) * scale;
    out[oi] = (out[oi] + emb[(NUSERS + iid[b]) * DIM + d]) * scale;
}

// ---------------- launch ----------------

extern "C" void kernel_launch(void* const* d_in, const int* in_sizes, int n_in,
                              void* d_out, int out_size, void* d_ws, size_t ws_size,
                              hipStream_t stream) {
    const float* users_emb = (const float*)d_in[0];
    const float* items_emb = (const float*)d_in[1];
    const int*   edge_row  = (const int*)d_in[2];
    const int*   edge_col  = (const int*)d_in[3];
    const int*   user_id   = (const int*)d_in[4];
    const int*   item_ids  = (const int*)d_in[5];
    float* out = (float*)d_out;

    char* ws = (char*)d_ws;
    // layout (bytes):
    //   dis   : [0, 600000)                      -> pad to 1 MiB
    //   w     : [1 MiB, 1 MiB + 16e6)            -> pad to 24 MiB
    //   emb_a : [24 MiB, 24 MiB + 38.4e6)        -> pad to 64 MiB
    //   emb_b : [64 MiB, 64 MiB + 38.4e6)
    float* dis   = (float*)(ws);
    float* w     = (float*)(ws + (size_t)(1)  * 1024 * 1024);
    float* emb_a = (float*)(ws + (size_t)(24) * 1024 * 1024);
    float* emb_b = (float*)(ws + (size_t)(64) * 1024 * 1024);

    // 1. degree
    hipMemsetAsync(dis, 0, (size_t)NN * sizeof(float), stream);
    k_degree<<<(NE + 255) / 256, 256, 0, stream>>>(edge_row, dis, NE);

    // 2. deg^{-1/2} in place
    k_inv_sqrt<<<(NN + 255) / 256, 256, 0, stream>>>(dis, NN);

    // 3. edge weights
    k_weights<<<(NE + 255) / 256, 256, 0, stream>>>(edge_row, edge_col, dis, w, NE);

    // 4. emb_a = concat(users, items)
    k_concat<<<(NN * DIM + 255) / 256, 256, 0, stream>>>(users_emb, items_emb, emb_a);

    // 5. layer-0 contribution into out
    k_gather_init<<<(BQ * DIM + 255) / 256, 256, 0, stream>>>(user_id, item_ids, emb_a, out);

    // 6. K hops
    float* cur = emb_a;
    float* nxt = emb_b;
    for (int h = 0; h < KHOPS; ++h) {
        hipMemsetAsync(nxt, 0, (size_t)NN * DIM * sizeof(float), stream);
        k_spmm<<<65536, 256, 0, stream>>>(edge_row, edge_col, w, cur, nxt, NE);
        float scale = (h == KHOPS - 1) ? (1.0f / (KHOPS + 1)) : 1.0f;
        k_gather_add<<<(BQ * DIM + 255) / 256, 256, 0, stream>>>(user_id, item_ids, nxt, out, scale);
        float* tmp = cur; cur = nxt; nxt = tmp;
    }
}

// Round 2
// 1088.665 us; speedup vs baseline: 2.5944x; 2.5944x over previous
//
#include <hip/hip_runtime.h>

#define NUSERS 100000
#define NITEMS 50000
#define NN (NUSERS + NITEMS)      // 150000
#define NE 4000000
#define DIM 64
#define BQ 4096
#define KHOPS 3

// ---------------- build kernels ----------------

__global__ void k_hist(const int* __restrict__ row, int* __restrict__ deg, int E) {
    int i = blockIdx.x * blockDim.x + threadIdx.x;
    if (i < E) atomicAdd(&deg[row[i]], 1);
}

__global__ void k_dis(const int* __restrict__ deg, float* __restrict__ dis, int N) {
    int i = blockIdx.x * blockDim.x + threadIdx.x;
    if (i < N) {
        int d = deg[i];
        dis[i] = (d > 0) ? (1.0f / sqrtf((float)d)) : 0.0f;
    }
}

// two-level exclusive scan of deg -> row_start
__global__ void k_scan1(const int* __restrict__ deg, int* __restrict__ rs,
                        int* __restrict__ bsum, int N) {
    __shared__ int s[256];
    int tid = threadIdx.x;
    int i = blockIdx.x * 256 + tid;
    int v = (i < N) ? deg[i] : 0;
    s[tid] = v;
    __syncthreads();
    for (int off = 1; off < 256; off <<= 1) {
        int t = (tid >= off) ? s[tid - off] : 0;
        __syncthreads();
        s[tid] += t;
        __syncthreads();
    }
    if (i < N) rs[i] = s[tid] - v;          // exclusive
    if (tid == 255) bsum[blockIdx.x] = s[255];
}

__global__ void k_scan2(int* __restrict__ bsum, int NB) {
    __shared__ int s[1024];
    int tid = threadIdx.x;
    int v = (tid < NB) ? bsum[tid] : 0;
    s[tid] = v;
    __syncthreads();
    for (int off = 1; off < 1024; off <<= 1) {
        int t = (tid >= off) ? s[tid - off] : 0;
        __syncthreads();
        s[tid] += t;
        __syncthreads();
    }
    if (tid < NB) bsum[tid] = s[tid] - v;   // exclusive
}

__global__ void k_scan3(int* __restrict__ rs, const int* __restrict__ bsum, int N) {
    int i = blockIdx.x * blockDim.x + threadIdx.x;
    if (i < N) rs[i] += bsum[i >> 8];
}

// scatter edges into CSR buckets; row_start[r] advances to end-of-bucket
// (spmm recovers start = row_start[r] - deg[r])
__global__ void k_fill(const int* __restrict__ row, const int* __restrict__ col,
                       int* __restrict__ rs, int* __restrict__ col_s, int E) {
    int e = blockIdx.x * blockDim.x + threadIdx.x;
    if (e < E) {
        int r = row[e];
        int pos = atomicAdd(&rs[r], 1);
        col_s[pos] = col[e];
    }
}

__global__ void k_concat(const float* __restrict__ u, const float* __restrict__ it,
                         float* __restrict__ emb) {
    int i = blockIdx.x * blockDim.x + threadIdx.x;
    const int NU = NUSERS * DIM;
    const int NT = NN * DIM;
    if (i < NU) emb[i] = u[i];
    else if (i < NT) emb[i] = it[i - NU];
}

// ---------------- SpMM: one wave per row, no atomics ----------------
// lane = 16*eslot + dq : 4 edges in flight, each lane reads a float4 (16B).
// acc accumulates sum_e dis[col_e] * in[col_e]; dis[row] applied at store.
__global__ void k_spmm_csr(const int* __restrict__ rs_end, const int* __restrict__ deg,
                           const float* __restrict__ dis, const int* __restrict__ col_s,
                           const float* __restrict__ in, float* __restrict__ out) {
    int wid = (blockIdx.x * blockDim.x + threadIdx.x) >> 6;
    if (wid >= NN) return;
    int lane = threadIdx.x & 63;
    int eslot = lane >> 4;   // 0..3
    int dq = lane & 15;      // dim quad (4 floats each)

    int n = deg[wid];
    int start = rs_end[wid] - n;   // rs advanced to bucket end during fill
    const float4* in4 = (const float4*)in;

    float4 acc = make_float4(0.0f, 0.0f, 0.0f, 0.0f);
    int nn = (n + 3) & ~3;
    for (int i = eslot; i < nn; i += 4) {
        int c = 0;
        float wv = 0.0f;
        if (i < n) {
            c = col_s[start + i];
            wv = dis[c];
        }
        float4 v = in4[(size_t)c * 16 + dq];
        acc.x += wv * v.x;
        acc.y += wv * v.y;
        acc.z += wv * v.z;
        acc.w += wv * v.w;
    }
    // reduce across the 4 edge slots (lanes lane^16, lane^32)
    for (int off = 16; off <= 32; off <<= 1) {
        acc.x += __shfl_xor(acc.x, off, 64);
        acc.y += __shfl_xor(acc.y, off, 64);
        acc.z += __shfl_xor(acc.z, off, 64);
        acc.w += __shfl_xor(acc.w, off, 64);
    }
    if (eslot == 0) {
        float dr = dis[wid];
        acc.x *= dr; acc.y *= dr; acc.z *= dr; acc.w *= dr;
        ((float4*)out)[(size_t)wid * 16 + dq] = acc;
    }
}

// ---------------- output gathers ----------------

__global__ void k_gather_init(const int* __restrict__ uid, const int* __restrict__ iid,
                              const float* __restrict__ emb, float* __restrict__ out) {
    int t = blockIdx.x * blockDim.x + threadIdx.x;
    if (t >= BQ * DIM) return;
    int b = t >> 6;
    int d = t & 63;
    out[b * (2 * DIM) + d]       = emb[(size_t)uid[b] * DIM + d];
    out[b * (2 * DIM) + DIM + d] = emb[(size_t)(NUSERS + iid[b]) * DIM + d];
}

__global__ void k_gather_add(const int* __restrict__ uid, const int* __restrict__ iid,
                             const float* __restrict__ emb, float* __restrict__ out,
                             float scale) {
    int t = blockIdx.x * blockDim.x + threadIdx.x;
    if (t >= BQ * DIM) return;
    int b = t >> 6;
    int d = t & 63;
    int ou = b * (2 * DIM) + d;
    int oi = ou + DIM;
    out[ou] = (out[ou] + emb[(size_t)uid[b] * DIM + d]) * scale;
    out[oi] = (out[oi] + emb[(size_t)(NUSERS + iid[b]) * DIM + d]) * scale;
}

// ---------------- launch ----------------

extern "C" void kernel_launch(void* const* d_in, const int* in_sizes, int n_in,
                              void* d_out, int out_size, void* d_ws, size_t ws_size,
                              hipStream_t stream) {
    const float* users_emb = (const float*)d_in[0];
    const float* items_emb = (const float*)d_in[1];
    const int*   edge_row  = (const int*)d_in[2];
    const int*   edge_col  = (const int*)d_in[3];
    const int*   user_id   = (const int*)d_in[4];
    const int*   item_ids  = (const int*)d_in[5];
    float* out = (float*)d_out;

    char* ws = (char*)d_ws;
    // byte layout (total < 98.5 MB, previous round used 102.4 MB OK):
    int*   deg_i = (int*)  (ws + 0);                       // 600 KB
    int*   rs    = (int*)  (ws + 655360);                  // 600 KB
    float* dis   = (float*)(ws + 1310720);                 // 600 KB
    int*   bsum  = (int*)  (ws + 1966080);                 // 4 KB
    int*   col_s = (int*)  (ws + 4194304);                 // 16 MB
    float* emb_a = (float*)(ws + 20971520);                // 38.4 MB
    float* emb_b = (float*)(ws + 60000000);                // 38.4 MB -> ends 98.4 MB

    const int NB = (NN + 255) / 256;   // 586

    // 1. degree histogram
    hipMemsetAsync(deg_i, 0, (size_t)NN * sizeof(int), stream);
    k_hist<<<(NE + 255) / 256, 256, 0, stream>>>(edge_row, deg_i, NE);

    // 2. dis = deg^{-1/2}
    k_dis<<<NB, 256, 0, stream>>>(deg_i, dis, NN);

    // 3. exclusive scan -> row_start
    k_scan1<<<NB, 256, 0, stream>>>(deg_i, rs, bsum, NN);
    k_scan2<<<1, 1024, 0, stream>>>(bsum, NB);
    k_scan3<<<NB, 256, 0, stream>>>(rs, bsum, NN);

    // 4. CSR fill (advances rs to bucket ends)
    k_fill<<<(NE + 255) / 256, 256, 0, stream>>>(edge_row, edge_col, rs, col_s, NE);

    // 5. emb_a = concat(users, items)
    k_concat<<<(NN * DIM + 255) / 256, 256, 0, stream>>>(users_emb, items_emb, emb_a);

    // 6. layer-0 contribution
    k_gather_init<<<(BQ * DIM + 255) / 256, 256, 0, stream>>>(user_id, item_ids, emb_a, out);

    // 7. K hops (one wave per row, 4 waves per 256-block)
    float* cur = emb_a;
    float* nxt = emb_b;
    const int spmm_blocks = (NN + 3) / 4;   // 37500
    for (int h = 0; h < KHOPS; ++h) {
        k_spmm_csr<<<spmm_blocks, 256, 0, stream>>>(rs, deg_i, dis, col_s, cur, nxt);
        float scale = (h == KHOPS - 1) ? (1.0f / (KHOPS + 1)) : 1.0f;
        k_gather_add<<<(BQ * DIM + 255) / 256, 256, 0, stream>>>(user_id, item_ids, nxt, out, scale);
        float* tmp = cur; cur = nxt; nxt = tmp;
    }
}

// Round 3
// 787.235 us; speedup vs baseline: 3.5879x; 1.3829x over previous
//
#include <hip/hip_runtime.h>

#define NUSERS 100000
#define NITEMS 50000
#define NN (NUSERS + NITEMS)      // 150000
#define NE 4000000
#define DIM 64
#define BQ 4096
#define KHOPS 3
#define NBIN ((NN + 255) >> 8)    // 586 bins of 256 rows
#define EPB 4096                  // edges per block in pass A

typedef unsigned short u16;

__device__ __forceinline__ float bf2f(u16 u) {
    return __uint_as_float(((unsigned)u) << 16);
}
__device__ __forceinline__ u16 f2bf(float f) {
    unsigned x = __float_as_uint(f);
    return (u16)((x + 0x7FFFu + ((x >> 16) & 1u)) >> 16);   // RNE
}

// ---------------- build kernels ----------------

__global__ void k_hist(const int* __restrict__ row, int* __restrict__ deg, int E) {
    int i = blockIdx.x * blockDim.x + threadIdx.x;
    if (i < E) atomicAdd(&deg[row[i]], 1);
}

__global__ void k_dis(const int* __restrict__ deg, float* __restrict__ dis, int N) {
    int i = blockIdx.x * blockDim.x + threadIdx.x;
    if (i < N) {
        int d = deg[i];
        dis[i] = (d > 0) ? (1.0f / sqrtf((float)d)) : 0.0f;
    }
}

// two-level exclusive scan of deg -> rs (pristine; never modified after)
__global__ void k_scan1(const int* __restrict__ deg, int* __restrict__ rs,
                        int* __restrict__ bsum, int N) {
    __shared__ int s[256];
    int tid = threadIdx.x;
    int i = blockIdx.x * 256 + tid;
    int v = (i < N) ? deg[i] : 0;
    s[tid] = v;
    __syncthreads();
    for (int off = 1; off < 256; off <<= 1) {
        int t = (tid >= off) ? s[tid - off] : 0;
        __syncthreads();
        s[tid] += t;
        __syncthreads();
    }
    if (i < N) rs[i] = s[tid] - v;
    if (tid == 255) bsum[blockIdx.x] = s[255];
}

__global__ void k_scan2(int* __restrict__ bsum, int NB) {
    __shared__ int s[1024];
    int tid = threadIdx.x;
    int v = (tid < NB) ? bsum[tid] : 0;
    s[tid] = v;
    __syncthreads();
    for (int off = 1; off < 1024; off <<= 1) {
        int t = (tid >= off) ? s[tid - off] : 0;
        __syncthreads();
        s[tid] += t;
        __syncthreads();
    }
    if (tid < NB) bsum[tid] = s[tid] - v;
}

__global__ void k_scan3(int* __restrict__ rs, const int* __restrict__ bsum, int N) {
    int i = blockIdx.x * blockDim.x + threadIdx.x;
    if (i < N) rs[i] += bsum[i >> 8];
}

__global__ void k_bininit(const int* __restrict__ rs, int* __restrict__ bin_cur) {
    int b = blockIdx.x * blockDim.x + threadIdx.x;
    if (b < NBIN) bin_cur[b] = rs[b << 8];
}

// Pass A: bin edges into 586 row-bins, dense chunk-append (full-line writes).
__global__ void k_binA(const int* __restrict__ row, const int* __restrict__ col,
                       int* __restrict__ bin_cur, uint2* __restrict__ pairs, int E) {
    __shared__ int hist[NBIN];
    __shared__ int cbase[NBIN];
    int t = threadIdx.x;
    for (int b = t; b < NBIN; b += 256) hist[b] = 0;
    __syncthreads();
    int base = blockIdx.x * EPB;
    int r[16], c[16];
#pragma unroll
    for (int i = 0; i < 16; ++i) {
        int e = base + i * 256 + t;
        if (e < E) {
            r[i] = row[e];
            c[i] = col[e];
            atomicAdd(&hist[r[i] >> 8], 1);
        } else {
            r[i] = -1;
        }
    }
    __syncthreads();
    for (int b = t; b < NBIN; b += 256) {
        int h = hist[b];
        cbase[b] = (h > 0) ? atomicAdd(&bin_cur[b], h) : 0;
    }
    __syncthreads();
#pragma unroll
    for (int i = 0; i < 16; ++i) {
        if (r[i] >= 0) {
            int b = r[i] >> 8;
            int off = atomicSub(&hist[b], 1) - 1;
            pairs[(size_t)cbase[b] + off] = make_uint2((unsigned)r[i], (unsigned)c[i]);
        }
    }
}

// Pass B: one block per bin; scatter cols to final CSR slots (L2-local window).
__global__ void k_binB(const uint2* __restrict__ pairs, const int* __restrict__ rs,
                       int* __restrict__ col_s) {
    __shared__ int cur[256];
    int b = blockIdx.x;
    int t = threadIdx.x;
    int r0 = b << 8;
    int rowsHere = NN - r0; if (rowsHere > 256) rowsHere = 256;
    if (t < rowsHere) cur[t] = rs[r0 + t];
    __syncthreads();
    int start = rs[r0];
    int end = (r0 + 256 < NN) ? rs[r0 + 256] : NE;
    for (int i = start + t; i < end; i += 256) {
        uint2 p = pairs[i];
        int pos = atomicAdd(&cur[p.x & 255], 1);
        col_s[pos] = (int)p.y;
    }
}

__global__ void k_concat_bf16(const float* __restrict__ u, const float* __restrict__ it,
                              u16* __restrict__ emb) {
    int i = blockIdx.x * blockDim.x + threadIdx.x;
    const int NU = NUSERS * DIM;
    const int NT = NN * DIM;
    if (i < NU) emb[i] = f2bf(u[i]);
    else if (i < NT) emb[i] = f2bf(it[i - NU]);
}

// ---------------- SpMM: one wave per row, bf16 in/out, fp32 accumulate ----------------
__global__ void k_spmm_bf16(const int* __restrict__ rs, const int* __restrict__ deg,
                            const float* __restrict__ dis, const int* __restrict__ col_s,
                            const u16* __restrict__ in, u16* __restrict__ out) {
    int wid = (blockIdx.x * blockDim.x + threadIdx.x) >> 6;
    if (wid >= NN) return;
    int lane = threadIdx.x & 63;
    int eslot = lane >> 4;   // 4 edges in flight
    int dq = lane & 15;      // 4 bf16 each -> 64 dims

    int n = deg[wid];
    int start = rs[wid];
    const ushort4* in4 = (const ushort4*)in;

    float4 acc = make_float4(0.0f, 0.0f, 0.0f, 0.0f);
    int nn = (n + 3) & ~3;
    for (int i = eslot; i < nn; i += 4) {
        int c = 0;
        float wv = 0.0f;
        if (i < n) {
            c = col_s[start + i];
            wv = dis[c];
        }
        ushort4 v = in4[(size_t)c * 16 + dq];
        acc.x += wv * bf2f(v.x);
        acc.y += wv * bf2f(v.y);
        acc.z += wv * bf2f(v.z);
        acc.w += wv * bf2f(v.w);
    }
    for (int off = 16; off <= 32; off <<= 1) {
        acc.x += __shfl_xor(acc.x, off, 64);
        acc.y += __shfl_xor(acc.y, off, 64);
        acc.z += __shfl_xor(acc.z, off, 64);
        acc.w += __shfl_xor(acc.w, off, 64);
    }
    if (eslot == 0) {
        float dr = dis[wid];
        ushort4 o;
        o.x = f2bf(acc.x * dr);
        o.y = f2bf(acc.y * dr);
        o.z = f2bf(acc.z * dr);
        o.w = f2bf(acc.w * dr);
        ((ushort4*)out)[(size_t)wid * 16 + dq] = o;
    }
}

// ---------------- output gathers ----------------

// layer-0 term straight from the pristine fp32 inputs (no quantization)
__global__ void k_gather_init(const int* __restrict__ uid, const int* __restrict__ iid,
                              const float* __restrict__ u, const float* __restrict__ it,
                              float* __restrict__ out) {
    int t = blockIdx.x * blockDim.x + threadIdx.x;
    if (t >= BQ * DIM) return;
    int b = t >> 6;
    int d = t & 63;
    out[b * (2 * DIM) + d]       = u[(size_t)uid[b] * DIM + d];
    out[b * (2 * DIM) + DIM + d] = it[(size_t)iid[b] * DIM + d];
}

__global__ void k_gather_add(const int* __restrict__ uid, const int* __restrict__ iid,
                             const u16* __restrict__ emb, float* __restrict__ out,
                             float scale) {
    int t = blockIdx.x * blockDim.x + threadIdx.x;
    if (t >= BQ * DIM) return;
    int b = t >> 6;
    int d = t & 63;
    int ou = b * (2 * DIM) + d;
    int oi = ou + DIM;
    out[ou] = (out[ou] + bf2f(emb[(size_t)uid[b] * DIM + d])) * scale;
    out[oi] = (out[oi] + bf2f(emb[(size_t)(NUSERS + iid[b]) * DIM + d])) * scale;
}

// ---------------- launch ----------------

extern "C" void kernel_launch(void* const* d_in, const int* in_sizes, int n_in,
                              void* d_out, int out_size, void* d_ws, size_t ws_size,
                              hipStream_t stream) {
    const float* users_emb = (const float*)d_in[0];
    const float* items_emb = (const float*)d_in[1];
    const int*   edge_row  = (const int*)d_in[2];
    const int*   edge_col  = (const int*)d_in[3];
    const int*   user_id   = (const int*)d_in[4];
    const int*   item_ids  = (const int*)d_in[5];
    float* out = (float*)d_out;

    char* ws = (char*)d_ws;
    // byte layout (ends ~94.7 MB):
    int*   deg_i   = (int*)  (ws + 0);           // 600 KB
    int*   rs      = (int*)  (ws + 655360);      // 600 KB
    float* dis     = (float*)(ws + 1310720);     // 600 KB
    int*   bsum    = (int*)  (ws + 1966080);     // 4 KB
    int*   bin_cur = (int*)  (ws + 2000000);     // 2.3 KB
    int*   col_s   = (int*)  (ws + 4194304);     // 16 MB
    uint2* pairs   = (uint2*)(ws + 20971520);    // 32 MB
    u16*   emb_a   = (u16*)  (ws + 54525952);    // 19.2 MB
    u16*   emb_b   = (u16*)  (ws + 75497472);    // 19.2 MB

    const int NB = (NN + 255) / 256;   // 586

    // degree histogram + dis
    hipMemsetAsync(deg_i, 0, (size_t)NN * sizeof(int), stream);
    k_hist<<<(NE + 255) / 256, 256, 0, stream>>>(edge_row, deg_i, NE);
    k_dis<<<NB, 256, 0, stream>>>(deg_i, dis, NN);

    // exclusive scan -> rs
    k_scan1<<<NB, 256, 0, stream>>>(deg_i, rs, bsum, NN);
    k_scan2<<<1, 1024, 0, stream>>>(bsum, NB);
    k_scan3<<<NB, 256, 0, stream>>>(rs, bsum, NN);

    // binned CSR build
    k_bininit<<<(NBIN + 255) / 256, 256, 0, stream>>>(rs, bin_cur);
    k_binA<<<(NE + EPB - 1) / EPB, 256, 0, stream>>>(edge_row, edge_col, bin_cur, pairs, NE);
    k_binB<<<NBIN, 256, 0, stream>>>(pairs, rs, col_s);

    // bf16 embedding table
    k_concat_bf16<<<(NN * DIM + 255) / 256, 256, 0, stream>>>(users_emb, items_emb, emb_a);

    // layer-0 contribution (fp32 sources)
    k_gather_init<<<(BQ * DIM + 255) / 256, 256, 0, stream>>>(user_id, item_ids,
                                                              users_emb, items_emb, out);

    // K hops
    u16* cur = emb_a;
    u16* nxt = emb_b;
    const int spmm_blocks = (NN + 3) / 4;
    for (int h = 0; h < KHOPS; ++h) {
        k_spmm_bf16<<<spmm_blocks, 256, 0, stream>>>(rs, deg_i, dis, col_s, cur, nxt);
        float scale = (h == KHOPS - 1) ? (1.0f / (KHOPS + 1)) : 1.0f;
        k_gather_add<<<(BQ * DIM + 255) / 256, 256, 0, stream>>>(user_id, item_ids, nxt, out, scale);
        u16* tmp = cur; cur = nxt; nxt = tmp;
    }
}

// Round 4
// 649.915 us; speedup vs baseline: 4.3459x; 1.2113x over previous
//
#include <hip/hip_runtime.h>

#define NUSERS 100000
#define NITEMS 50000
#define NN (NUSERS + NITEMS)      // 150000
#define NE 4000000
#define DIM 64
#define BQ 4096
#define KHOPS 3
#define NBIN ((NN + 255) >> 8)    // 586 bins of 256 rows
#define EPB 4096                  // edges per block in pass A
#define CNT_BLOCKS 512

typedef unsigned short u16;
typedef unsigned int u32;

__device__ __forceinline__ float bf2f(u16 u) {
    return __uint_as_float(((unsigned)u) << 16);
}
__device__ __forceinline__ u16 f2bf(float f) {
    unsigned x = __float_as_uint(f);
    return (u16)((x + 0x7FFFu + ((x >> 16) & 1u)) >> 16);   // RNE
}

// ---------------- build kernels ----------------

// Per-block LDS histogram of the 586 row-bins; one global atomicAdd per (block,bin).
__global__ void k_bincount(const int* __restrict__ row, int* __restrict__ bin_cnt, int E) {
    __shared__ int h[NBIN];
    int t = threadIdx.x;
    for (int b = t; b < NBIN; b += 256) h[b] = 0;
    __syncthreads();
    int per = (E + CNT_BLOCKS - 1) / CNT_BLOCKS;
    int base = blockIdx.x * per;
    int lim = base + per; if (lim > E) lim = E;
    for (int e = base + t; e < lim; e += 256)
        atomicAdd(&h[row[e] >> 8], 1);
    __syncthreads();
    for (int b = t; b < NBIN; b += 256)
        if (h[b] > 0) atomicAdd(&bin_cnt[b], h[b]);
}

// Single-block exclusive scan of bin_cnt -> bin_base[NBIN+1], bin_cur copy.
__global__ void k_binscan(const int* __restrict__ bin_cnt, int* __restrict__ bin_base,
                          int* __restrict__ bin_cur) {
    __shared__ int s[1024];
    int t = threadIdx.x;
    int v = (t < NBIN) ? bin_cnt[t] : 0;
    s[t] = v;
    __syncthreads();
    for (int off = 1; off < 1024; off <<= 1) {
        int x = (t >= off) ? s[t - off] : 0;
        __syncthreads();
        s[t] += x;
        __syncthreads();
    }
    if (t < NBIN) {
        int excl = s[t] - v;
        bin_base[t] = excl;
        bin_cur[t] = excl;
        if (t == NBIN - 1) bin_base[NBIN] = s[t];
    }
}

// Pass A: bin edges into 586 row-bins, dense chunk-append. Packed u32:
// (row&255)<<24 | col   (col < 150000 < 2^24)
__global__ void k_binA(const int* __restrict__ row, const int* __restrict__ col,
                       int* __restrict__ bin_cur, u32* __restrict__ pairs, int E) {
    __shared__ int hist[NBIN];
    __shared__ int cbase[NBIN];
    int t = threadIdx.x;
    for (int b = t; b < NBIN; b += 256) hist[b] = 0;
    __syncthreads();
    int base = blockIdx.x * EPB;
    int r[16], c[16];
#pragma unroll
    for (int i = 0; i < 16; ++i) {
        int e = base + i * 256 + t;
        if (e < E) {
            r[i] = row[e];
            c[i] = col[e];
            atomicAdd(&hist[r[i] >> 8], 1);
        } else {
            r[i] = -1;
        }
    }
    __syncthreads();
    for (int b = t; b < NBIN; b += 256) {
        int h = hist[b];
        cbase[b] = (h > 0) ? atomicAdd(&bin_cur[b], h) : 0;
    }
    __syncthreads();
#pragma unroll
    for (int i = 0; i < 16; ++i) {
        if (r[i] >= 0) {
            int b = r[i] >> 8;
            int off = atomicSub(&hist[b], 1) - 1;
            pairs[(size_t)cbase[b] + off] = ((u32)(r[i] & 255) << 24) | (u32)c[i];
        }
    }
}

// Pass B: one block per bin. Derives deg/rs/dis from the bin's pairs, then
// scatters cols to final CSR slots (L2-local window).
__global__ void k_binB(const u32* __restrict__ pairs, const int* __restrict__ bin_base,
                       int* __restrict__ col_s, int* __restrict__ rs,
                       int* __restrict__ deg, float* __restrict__ dis) {
    __shared__ int cnt[256];
    __shared__ int cur[256];
    int b = blockIdx.x;
    int t = threadIdx.x;
    cnt[t] = 0;
    __syncthreads();
    int start = bin_base[b];
    int end = bin_base[b + 1];
    for (int i = start + t; i < end; i += 256)
        atomicAdd(&cnt[pairs[i] >> 24], 1);
    __syncthreads();
    // Hillis-Steele exclusive scan of cnt
    int v = cnt[t];
    cur[t] = v;
    __syncthreads();
    for (int off = 1; off < 256; off <<= 1) {
        int x = (t >= off) ? cur[t - off] : 0;
        __syncthreads();
        cur[t] += x;
        __syncthreads();
    }
    int rowstart = start + cur[t] - v;
    int r = (b << 8) + t;
    if (r < NN) {
        rs[r] = rowstart;
        deg[r] = v;
        dis[r] = (v > 0) ? (1.0f / sqrtf((float)v)) : 0.0f;
    }
    cur[t] = rowstart;
    __syncthreads();
    for (int i = start + t; i < end; i += 256) {
        u32 p = pairs[i];
        int pos = atomicAdd(&cur[p >> 24], 1);
        col_s[pos] = (int)(p & 0x00FFFFFFu);
    }
}

__global__ void k_concat_bf16(const float* __restrict__ u, const float* __restrict__ it,
                              u16* __restrict__ emb) {
    int i = blockIdx.x * blockDim.x + threadIdx.x;
    const int NU = NUSERS * DIM;
    const int NT = NN * DIM;
    if (i < NU) emb[i] = f2bf(u[i]);
    else if (i < NT) emb[i] = f2bf(it[i - NU]);
}

// ---------------- SpMM: one wave per row, bf16 in/out, fp32 accumulate ----------------
__global__ void k_spmm_bf16(const int* __restrict__ rs, const int* __restrict__ deg,
                            const float* __restrict__ dis, const int* __restrict__ col_s,
                            const u16* __restrict__ in, u16* __restrict__ out) {
    int wid = (blockIdx.x * blockDim.x + threadIdx.x) >> 6;
    if (wid >= NN) return;
    int lane = threadIdx.x & 63;
    int eslot = lane >> 4;   // 4 edges in flight
    int dq = lane & 15;      // 4 bf16 each -> 64 dims

    int n = deg[wid];
    int start = rs[wid];
    const ushort4* in4 = (const ushort4*)in;

    float4 acc = make_float4(0.0f, 0.0f, 0.0f, 0.0f);
    int nn = (n + 3) & ~3;
    for (int i = eslot; i < nn; i += 4) {
        int c = 0;
        float wv = 0.0f;
        if (i < n) {
            c = col_s[start + i];
            wv = dis[c];
        }
        ushort4 v = in4[(size_t)c * 16 + dq];
        acc.x += wv * bf2f(v.x);
        acc.y += wv * bf2f(v.y);
        acc.z += wv * bf2f(v.z);
        acc.w += wv * bf2f(v.w);
    }
    for (int off = 16; off <= 32; off <<= 1) {
        acc.x += __shfl_xor(acc.x, off, 64);
        acc.y += __shfl_xor(acc.y, off, 64);
        acc.z += __shfl_xor(acc.z, off, 64);
        acc.w += __shfl_xor(acc.w, off, 64);
    }
    if (eslot == 0) {
        float dr = dis[wid];
        ushort4 o;
        o.x = f2bf(acc.x * dr);
        o.y = f2bf(acc.y * dr);
        o.z = f2bf(acc.z * dr);
        o.w = f2bf(acc.w * dr);
        ((ushort4*)out)[(size_t)wid * 16 + dq] = o;
    }
}

// ---------------- output gathers ----------------

__global__ void k_gather_init(const int* __restrict__ uid, const int* __restrict__ iid,
                              const float* __restrict__ u, const float* __restrict__ it,
                              float* __restrict__ out) {
    int t = blockIdx.x * blockDim.x + threadIdx.x;
    if (t >= BQ * DIM) return;
    int b = t >> 6;
    int d = t & 63;
    out[b * (2 * DIM) + d]       = u[(size_t)uid[b] * DIM + d];
    out[b * (2 * DIM) + DIM + d] = it[(size_t)iid[b] * DIM + d];
}

__global__ void k_gather_add(const int* __restrict__ uid, const int* __restrict__ iid,
                             const u16* __restrict__ emb, float* __restrict__ out,
                             float scale) {
    int t = blockIdx.x * blockDim.x + threadIdx.x;
    if (t >= BQ * DIM) return;
    int b = t >> 6;
    int d = t & 63;
    int ou = b * (2 * DIM) + d;
    int oi = ou + DIM;
    out[ou] = (out[ou] + bf2f(emb[(size_t)uid[b] * DIM + d])) * scale;
    out[oi] = (out[oi] + bf2f(emb[(size_t)(NUSERS + iid[b]) * DIM + d])) * scale;
}

// ---------------- launch ----------------

extern "C" void kernel_launch(void* const* d_in, const int* in_sizes, int n_in,
                              void* d_out, int out_size, void* d_ws, size_t ws_size,
                              hipStream_t stream) {
    const float* users_emb = (const float*)d_in[0];
    const float* items_emb = (const float*)d_in[1];
    const int*   edge_row  = (const int*)d_in[2];
    const int*   edge_col  = (const int*)d_in[3];
    const int*   user_id   = (const int*)d_in[4];
    const int*   item_ids  = (const int*)d_in[5];
    float* out = (float*)d_out;

    char* ws = (char*)d_ws;
    // byte layout (ends ~78 MB):
    int*   deg_i    = (int*)  (ws + 0);           // 600 KB
    int*   rs       = (int*)  (ws + 655360);      // 600 KB
    float* dis      = (float*)(ws + 1310720);     // 600 KB
    int*   bin_cnt  = (int*)  (ws + 1966080);     // 2.4 KB
    int*   bin_base = (int*)  (ws + 1970176);     // 2.4 KB
    int*   bin_cur  = (int*)  (ws + 1974272);     // 2.4 KB
    int*   col_s    = (int*)  (ws + 4194304);     // 16 MB
    u32*   pairs    = (u32*)  (ws + 20971520);    // 16 MB
    u16*   emb_a    = (u16*)  (ws + 37748736);    // 19.2 MB
    u16*   emb_b    = (u16*)  (ws + 58720256);    // 19.2 MB -> ends 77.9 MB

    // bin counts -> bases
    hipMemsetAsync(bin_cnt, 0, NBIN * sizeof(int), stream);
    k_bincount<<<CNT_BLOCKS, 256, 0, stream>>>(edge_row, bin_cnt, NE);
    k_binscan<<<1, 1024, 0, stream>>>(bin_cnt, bin_base, bin_cur);

    // binned CSR build (derives deg/rs/dis in pass B)
    k_binA<<<(NE + EPB - 1) / EPB, 256, 0, stream>>>(edge_row, edge_col, bin_cur, pairs, NE);
    k_binB<<<NBIN, 256, 0, stream>>>(pairs, bin_base, col_s, rs, deg_i, dis);

    // bf16 embedding table
    k_concat_bf16<<<(NN * DIM + 255) / 256, 256, 0, stream>>>(users_emb, items_emb, emb_a);

    // layer-0 contribution (fp32 sources)
    k_gather_init<<<(BQ * DIM + 255) / 256, 256, 0, stream>>>(user_id, item_ids,
                                                              users_emb, items_emb, out);

    // K hops
    u16* cur = emb_a;
    u16* nxt = emb_b;
    const int spmm_blocks = (NN + 3) / 4;
    for (int h = 0; h < KHOPS; ++h) {
        k_spmm_bf16<<<spmm_blocks, 256, 0, stream>>>(rs, deg_i, dis, col_s, cur, nxt);
        float scale = (h == KHOPS - 1) ? (1.0f / (KHOPS + 1)) : 1.0f;
        k_gather_add<<<(BQ * DIM + 255) / 256, 256, 0, stream>>>(user_id, item_ids, nxt, out, scale);
        u16* tmp = cur; cur = nxt; nxt = tmp;
    }
}

// Round 5
// 444.927 us; speedup vs baseline: 6.3482x; 1.4607x over previous
//
#include <hip/hip_runtime.h>

#define NUSERS 100000
#define NITEMS 50000
#define NN (NUSERS + NITEMS)      // 150000
#define NE 4000000
#define DIM 64
#define BQ 4096
#define KHOPS 3
#define NBIN ((NN + 255) >> 8)    // 586 bins of 256 rows
#define EPB 4096                  // edges per block in pass A
#define CNT_BLOCKS 512

typedef unsigned short u16;
typedef unsigned int u32;

__device__ __forceinline__ float bf2f(u16 u) {
    return __uint_as_float(((unsigned)u) << 16);
}
__device__ __forceinline__ u16 f2bf(float f) {
    unsigned x = __float_as_uint(f);
    return (u16)((x + 0x7FFFu + ((x >> 16) & 1u)) >> 16);   // RNE
}
__device__ __forceinline__ void accum8(float* acc, uint4 u, float wv) {
    acc[0] += wv * __uint_as_float(u.x << 16);
    acc[1] += wv * __uint_as_float(u.x & 0xffff0000u);
    acc[2] += wv * __uint_as_float(u.y << 16);
    acc[3] += wv * __uint_as_float(u.y & 0xffff0000u);
    acc[4] += wv * __uint_as_float(u.z << 16);
    acc[5] += wv * __uint_as_float(u.z & 0xffff0000u);
    acc[6] += wv * __uint_as_float(u.w << 16);
    acc[7] += wv * __uint_as_float(u.w & 0xffff0000u);
}

// ---------------- build kernels ----------------

__global__ void k_bincount(const int* __restrict__ row, int* __restrict__ bin_cnt, int E) {
    __shared__ int h[NBIN];
    int t = threadIdx.x;
    for (int b = t; b < NBIN; b += 256) h[b] = 0;
    __syncthreads();
    int per = (E + CNT_BLOCKS - 1) / CNT_BLOCKS;
    int base = blockIdx.x * per;
    int lim = base + per; if (lim > E) lim = E;
    for (int e = base + t; e < lim; e += 256)
        atomicAdd(&h[row[e] >> 8], 1);
    __syncthreads();
    for (int b = t; b < NBIN; b += 256)
        if (h[b] > 0) atomicAdd(&bin_cnt[b], h[b]);
}

__global__ void k_binscan(const int* __restrict__ bin_cnt, int* __restrict__ bin_base,
                          int* __restrict__ bin_cur) {
    __shared__ int s[1024];
    int t = threadIdx.x;
    int v = (t < NBIN) ? bin_cnt[t] : 0;
    s[t] = v;
    __syncthreads();
    for (int off = 1; off < 1024; off <<= 1) {
        int x = (t >= off) ? s[t - off] : 0;
        __syncthreads();
        s[t] += x;
        __syncthreads();
    }
    if (t < NBIN) {
        int excl = s[t] - v;
        bin_base[t] = excl;
        bin_cur[t] = excl;
        if (t == NBIN - 1) bin_base[NBIN] = s[t];
    }
}

// Pass A: bin edges, dense chunk-append. Packed u32: (row&255)<<24 | col.
__global__ void k_binA(const int* __restrict__ row, const int* __restrict__ col,
                       int* __restrict__ bin_cur, u32* __restrict__ pairs, int E) {
    __shared__ int hist[NBIN];
    __shared__ int cbase[NBIN];
    int t = threadIdx.x;
    for (int b = t; b < NBIN; b += 256) hist[b] = 0;
    __syncthreads();
    int base = blockIdx.x * EPB;
    int r[16], c[16];
#pragma unroll
    for (int i = 0; i < 16; ++i) {
        int e = base + i * 256 + t;
        if (e < E) {
            r[i] = row[e];
            c[i] = col[e];
            atomicAdd(&hist[r[i] >> 8], 1);
        } else {
            r[i] = -1;
        }
    }
    __syncthreads();
    for (int b = t; b < NBIN; b += 256) {
        int h = hist[b];
        cbase[b] = (h > 0) ? atomicAdd(&bin_cur[b], h) : 0;
    }
    __syncthreads();
#pragma unroll
    for (int i = 0; i < 16; ++i) {
        if (r[i] >= 0) {
            int b = r[i] >> 8;
            int off = atomicSub(&hist[b], 1) - 1;
            pairs[(size_t)cbase[b] + off] = ((u32)(r[i] & 255) << 24) | (u32)c[i];
        }
    }
}

// Pass B: derives deg/rs/dis per bin, then scatters cols (L2-local window).
__global__ void k_binB(const u32* __restrict__ pairs, const int* __restrict__ bin_base,
                       int* __restrict__ col_s, int* __restrict__ rs,
                       int* __restrict__ deg, float* __restrict__ dis) {
    __shared__ int cnt[256];
    __shared__ int cur[256];
    int b = blockIdx.x;
    int t = threadIdx.x;
    cnt[t] = 0;
    __syncthreads();
    int start = bin_base[b];
    int end = bin_base[b + 1];
    for (int i = start + t; i < end; i += 256)
        atomicAdd(&cnt[pairs[i] >> 24], 1);
    __syncthreads();
    int v = cnt[t];
    cur[t] = v;
    __syncthreads();
    for (int off = 1; off < 256; off <<= 1) {
        int x = (t >= off) ? cur[t - off] : 0;
        __syncthreads();
        cur[t] += x;
        __syncthreads();
    }
    int rowstart = start + cur[t] - v;
    int r = (b << 8) + t;
    if (r < NN) {
        rs[r] = rowstart;
        deg[r] = v;
        dis[r] = (v > 0) ? (1.0f / sqrtf((float)v)) : 0.0f;
    }
    cur[t] = rowstart;
    __syncthreads();
    for (int i = start + t; i < end; i += 256) {
        u32 p = pairs[i];
        int pos = atomicAdd(&cur[p >> 24], 1);
        col_s[pos] = (int)(p & 0x00FFFFFFu);
    }
}

__global__ void k_concat_bf16(const float* __restrict__ u, const float* __restrict__ it,
                              u16* __restrict__ emb) {
    int i = blockIdx.x * blockDim.x + threadIdx.x;   // ushort4 index
    const int NU4 = NUSERS * DIM / 4;
    const int NT4 = NN * DIM / 4;
    if (i >= NT4) return;
    float4 v = (i < NU4) ? ((const float4*)u)[i] : ((const float4*)it)[i - NU4];
    ushort4 o;
    o.x = f2bf(v.x); o.y = f2bf(v.y); o.z = f2bf(v.z); o.w = f2bf(v.w);
    ((ushort4*)emb)[i] = o;
}

// mark rows needed for hop-2 output: query rows + their CSR neighbors
__global__ void k_mark(const int* __restrict__ uid, const int* __restrict__ iid,
                       const int* __restrict__ rs, const int* __restrict__ deg,
                       const int* __restrict__ col_s, unsigned char* __restrict__ m2) {
    int q = blockIdx.x * blockDim.x + threadIdx.x;
    if (q >= 2 * BQ) return;
    int r = (q < BQ) ? uid[q] : (NUSERS + iid[q - BQ]);
    m2[r] = 1;
    int s = rs[r], n = deg[r];
    for (int i = 0; i < n; ++i) m2[col_s[s + i]] = 1;
}

// ---------------- SpMM: one wave per row, 8 edges in flight ----------------
// lane = eslot*8 + dg : eslot in [0,8), dg in [0,8). Each lane loads uint4
// (8 bf16 = dims [dg*8, dg*8+8)). fp32 accumulate, dis[row] at store.
__global__ void k_spmm8(const int* __restrict__ rs, const int* __restrict__ deg,
                        const float* __restrict__ dis, const int* __restrict__ col_s,
                        const u16* __restrict__ in, u16* __restrict__ out,
                        const unsigned char* __restrict__ mask) {
    int wid = (blockIdx.x * blockDim.x + threadIdx.x) >> 6;
    if (wid >= NN) return;
    if (mask && !mask[wid]) return;
    int lane = threadIdx.x & 63;
    int eslot = lane >> 3;
    int dg = lane & 7;
    int n = deg[wid];
    int start = rs[wid];
    const uint4* in4 = (const uint4*)in;
    float acc[8] = {0, 0, 0, 0, 0, 0, 0, 0};
    int nn8 = (n + 7) & ~7;
    for (int i = eslot; i < nn8; i += 8) {
        int c = 0;
        float wv = 0.0f;
        if (i < n) {
            c = col_s[start + i];
            wv = dis[c];
        }
        uint4 v = in4[(size_t)c * 8 + dg];
        accum8(acc, v, wv);
    }
#pragma unroll
    for (int off = 8; off <= 32; off <<= 1)
#pragma unroll
        for (int j = 0; j < 8; ++j)
            acc[j] += __shfl_xor(acc[j], off, 64);
    if (eslot == 0) {
        float dr = dis[wid];
        u32 p0 = (u32)f2bf(acc[0] * dr) | ((u32)f2bf(acc[1] * dr) << 16);
        u32 p1 = (u32)f2bf(acc[2] * dr) | ((u32)f2bf(acc[3] * dr) << 16);
        u32 p2 = (u32)f2bf(acc[4] * dr) | ((u32)f2bf(acc[5] * dr) << 16);
        u32 p3 = (u32)f2bf(acc[6] * dr) | ((u32)f2bf(acc[7] * dr) << 16);
        ((uint4*)out)[(size_t)wid * 8 + dg] = make_uint4(p0, p1, p2, p3);
    }
}

// hop-3 fused: one wave per query slot, accumulates (out + dis[r]*sum)*0.25
__global__ void k_spmm_out(const int* __restrict__ rs, const int* __restrict__ deg,
                           const float* __restrict__ dis, const int* __restrict__ col_s,
                           const u16* __restrict__ in,
                           const int* __restrict__ uid, const int* __restrict__ iid,
                           float* __restrict__ out) {
    int q = (blockIdx.x * blockDim.x + threadIdx.x) >> 6;
    if (q >= 2 * BQ) return;
    int lane = threadIdx.x & 63;
    int eslot = lane >> 3;
    int dg = lane & 7;
    int b, r, off;
    if (q < BQ) { b = q; r = uid[q]; off = 0; }
    else { b = q - BQ; r = NUSERS + iid[q - BQ]; off = DIM; }
    int n = deg[r];
    int start = rs[r];
    const uint4* in4 = (const uint4*)in;
    float acc[8] = {0, 0, 0, 0, 0, 0, 0, 0};
    int nn8 = (n + 7) & ~7;
    for (int i = eslot; i < nn8; i += 8) {
        int c = 0;
        float wv = 0.0f;
        if (i < n) {
            c = col_s[start + i];
            wv = dis[c];
        }
        uint4 v = in4[(size_t)c * 8 + dg];
        accum8(acc, v, wv);
    }
#pragma unroll
    for (int off2 = 8; off2 <= 32; off2 <<= 1)
#pragma unroll
        for (int j = 0; j < 8; ++j)
            acc[j] += __shfl_xor(acc[j], off2, 64);
    if (eslot == 0) {
        float dr = dis[r];
        float* o = out + (size_t)b * (2 * DIM) + off + dg * 8;
#pragma unroll
        for (int j = 0; j < 8; ++j)
            o[j] = (o[j] + dr * acc[j]) * 0.25f;
    }
}

// ---------------- output gathers ----------------

__global__ void k_gather_init(const int* __restrict__ uid, const int* __restrict__ iid,
                              const float* __restrict__ u, const float* __restrict__ it,
                              float* __restrict__ out) {
    int t = blockIdx.x * blockDim.x + threadIdx.x;
    if (t >= BQ * DIM) return;
    int b = t >> 6;
    int d = t & 63;
    out[b * (2 * DIM) + d]       = u[(size_t)uid[b] * DIM + d];
    out[b * (2 * DIM) + DIM + d] = it[(size_t)iid[b] * DIM + d];
}

__global__ void k_gather_add(const int* __restrict__ uid, const int* __restrict__ iid,
                             const u16* __restrict__ emb, float* __restrict__ out) {
    int t = blockIdx.x * blockDim.x + threadIdx.x;
    if (t >= BQ * DIM) return;
    int b = t >> 6;
    int d = t & 63;
    int ou = b * (2 * DIM) + d;
    int oi = ou + DIM;
    out[ou] = out[ou] + bf2f(emb[(size_t)uid[b] * DIM + d]);
    out[oi] = out[oi] + bf2f(emb[(size_t)(NUSERS + iid[b]) * DIM + d]);
}

// ---------------- launch ----------------

extern "C" void kernel_launch(void* const* d_in, const int* in_sizes, int n_in,
                              void* d_out, int out_size, void* d_ws, size_t ws_size,
                              hipStream_t stream) {
    const float* users_emb = (const float*)d_in[0];
    const float* items_emb = (const float*)d_in[1];
    const int*   edge_row  = (const int*)d_in[2];
    const int*   edge_col  = (const int*)d_in[3];
    const int*   user_id   = (const int*)d_in[4];
    const int*   item_ids  = (const int*)d_in[5];
    float* out = (float*)d_out;

    char* ws = (char*)d_ws;
    int*   deg_i    = (int*)  (ws + 0);           // 600 KB
    int*   rs       = (int*)  (ws + 655360);      // 600 KB
    float* dis      = (float*)(ws + 1310720);     // 600 KB
    int*   bin_cnt  = (int*)  (ws + 1966080);     // 2.4 KB
    int*   bin_base = (int*)  (ws + 1970176);     // 2.4 KB
    int*   bin_cur  = (int*)  (ws + 1974272);     // 2.4 KB
    unsigned char* m2 = (unsigned char*)(ws + 1978368);  // 150 KB
    int*   col_s    = (int*)  (ws + 4194304);     // 16 MB
    u32*   pairs    = (u32*)  (ws + 20971520);    // 16 MB
    u16*   emb_a    = (u16*)  (ws + 37748736);    // 19.2 MB
    u16*   emb_b    = (u16*)  (ws + 58720256);    // 19.2 MB -> ends 77.9 MB

    // bin counts -> bases
    hipMemsetAsync(bin_cnt, 0, NBIN * sizeof(int), stream);
    hipMemsetAsync(m2, 0, NN, stream);
    k_bincount<<<CNT_BLOCKS, 256, 0, stream>>>(edge_row, bin_cnt, NE);
    k_binscan<<<1, 1024, 0, stream>>>(bin_cnt, bin_base, bin_cur);

    // binned CSR build (derives deg/rs/dis in pass B)
    k_binA<<<(NE + EPB - 1) / EPB, 256, 0, stream>>>(edge_row, edge_col, bin_cur, pairs, NE);
    k_binB<<<NBIN, 256, 0, stream>>>(pairs, bin_base, col_s, rs, deg_i, dis);

    // bf16 embedding table
    k_concat_bf16<<<(NN * DIM / 4 + 255) / 256, 256, 0, stream>>>(users_emb, items_emb, emb_a);

    // layer-0 contribution (fp32 sources)
    k_gather_init<<<(BQ * DIM + 255) / 256, 256, 0, stream>>>(user_id, item_ids,
                                                              users_emb, items_emb, out);

    // mark rows whose hop-2 output is actually read
    k_mark<<<(2 * BQ + 255) / 256, 256, 0, stream>>>(user_id, item_ids, rs, deg_i, col_s, m2);

    const int spmm_blocks = (NN + 3) / 4;
    // hop 1: full
    k_spmm8<<<spmm_blocks, 256, 0, stream>>>(rs, deg_i, dis, col_s, emb_a, emb_b,
                                             (const unsigned char*)nullptr);
    k_gather_add<<<(BQ * DIM + 255) / 256, 256, 0, stream>>>(user_id, item_ids, emb_b, out);
    // hop 2: masked (only rows read by hop-3 / gather)
    k_spmm8<<<spmm_blocks, 256, 0, stream>>>(rs, deg_i, dis, col_s, emb_b, emb_a, m2);
    k_gather_add<<<(BQ * DIM + 255) / 256, 256, 0, stream>>>(user_id, item_ids, emb_a, out);
    // hop 3: fused into output, fp32 accumulate, final /4
    k_spmm_out<<<(2 * BQ + 3) / 4, 256, 0, stream>>>(rs, deg_i, dis, col_s, emb_a,
                                                     user_id, item_ids, out);
}

// Round 6
// 375.632 us; speedup vs baseline: 7.5193x; 1.1845x over previous
//
#include <hip/hip_runtime.h>

#define NUSERS 100000
#define NITEMS 50000
#define NN (NUSERS + NITEMS)      // 150000
#define NE 4000000
#define DIM 64
#define BQ 4096
#define NBIN ((NN + 255) >> 8)    // 586 bins of 256 rows
#define BINCAP 9216               // fixed slots/bin; mean 6827, sigma 83 -> 16 sigma margin
#define EPB 4096                  // edges per block in pass A

typedef unsigned short u16;
typedef unsigned int u32;

__device__ __forceinline__ float bf2f(u16 u) {
    return __uint_as_float(((unsigned)u) << 16);
}
__device__ __forceinline__ u16 f2bf(float f) {
    unsigned x = __float_as_uint(f);
    return (u16)((x + 0x7FFFu + ((x >> 16) & 1u)) >> 16);   // RNE
}
// unpack uint4 (8 bf16) and accumulate (pure adds — weights folded into t-space)
__device__ __forceinline__ void add8(float* acc, uint4 u) {
    acc[0] += __uint_as_float(u.x << 16);
    acc[1] += __uint_as_float(u.x & 0xffff0000u);
    acc[2] += __uint_as_float(u.y << 16);
    acc[3] += __uint_as_float(u.y & 0xffff0000u);
    acc[4] += __uint_as_float(u.z << 16);
    acc[5] += __uint_as_float(u.z & 0xffff0000u);
    acc[6] += __uint_as_float(u.w << 16);
    acc[7] += __uint_as_float(u.w & 0xffff0000u);
}

// ---------------- init: bin cursors, m2 mask, sentinel rows ----------------
__global__ void k_init(int* __restrict__ bin_cur, u32* __restrict__ m2w,
                       u16* __restrict__ ea, u16* __restrict__ eb) {
    int t = blockIdx.x * blockDim.x + threadIdx.x;
    if (t < NBIN) bin_cur[t] = t * BINCAP;
    if (t < 37504) m2w[t] = 0;                 // zero 150016 bytes of m2
    if (t < 32) {                              // zero sentinel row NN in both tables
        ((u32*)(ea + (size_t)NN * DIM))[t] = 0;
        ((u32*)(eb + (size_t)NN * DIM))[t] = 0;
    }
}

// ---------------- Pass A: bin edges, dense chunk-append ----------------
// Packed u32: (row&255)<<24 | col  (col < 150000 < 2^24)
__global__ void k_binA(const int* __restrict__ row, const int* __restrict__ col,
                       int* __restrict__ bin_cur, u32* __restrict__ pairs, int E) {
    __shared__ int hist[NBIN];
    __shared__ int cbase[NBIN];
    int t = threadIdx.x;
    for (int b = t; b < NBIN; b += 256) hist[b] = 0;
    __syncthreads();
    int base = blockIdx.x * EPB;
    int r[16], c[16];
#pragma unroll
    for (int i = 0; i < 16; ++i) {
        int e = base + i * 256 + t;
        if (e < E) {
            r[i] = row[e];
            c[i] = col[e];
            atomicAdd(&hist[r[i] >> 8], 1);
        } else {
            r[i] = -1;
        }
    }
    __syncthreads();
    for (int b = t; b < NBIN; b += 256) {
        int h = hist[b];
        cbase[b] = (h > 0) ? atomicAdd(&bin_cur[b], h) : 0;
    }
    __syncthreads();
#pragma unroll
    for (int i = 0; i < 16; ++i) {
        if (r[i] >= 0) {
            int b = r[i] >> 8;
            int off = atomicSub(&hist[b], 1) - 1;
            pairs[(size_t)cbase[b] + off] = ((u32)(r[i] & 255) << 24) | (u32)c[i];
        }
    }
}

// ---------------- Pass B: per-bin row sort; derives rs/deg; pads to 8 ----------------
__global__ void k_binB(const u32* __restrict__ pairs, const int* __restrict__ bin_cur,
                       int* __restrict__ col_s, int* __restrict__ rs,
                       int* __restrict__ deg) {
    __shared__ int cnt[256];
    __shared__ int pscan[256];
    __shared__ int cur[256];
    int b = blockIdx.x;
    int t = threadIdx.x;
    int base = b * BINCAP;
    int end = bin_cur[b];
    cnt[t] = 0;
    __syncthreads();
    for (int i = base + t; i < end; i += 256)
        atomicAdd(&cnt[pairs[i] >> 24], 1);
    __syncthreads();
    int v = cnt[t];
    int pv = (v + 7) & ~7;                    // row segment padded to multiple of 8
    pscan[t] = pv;
    __syncthreads();
    for (int off = 1; off < 256; off <<= 1) {
        int x = (t >= off) ? pscan[t - off] : 0;
        __syncthreads();
        pscan[t] += x;
        __syncthreads();
    }
    int rowstart = base + pscan[t] - pv;
    int r = (b << 8) + t;
    if (r < NN) {
        rs[r] = rowstart;
        deg[r] = v;
    }
    cur[t] = rowstart;
    for (int i = v; i < pv; ++i) col_s[rowstart + i] = NN;   // sentinel pads
    __syncthreads();
    for (int i = base + t; i < end; i += 256) {
        u32 p = pairs[i];
        int pos = atomicAdd(&cur[p >> 24], 1);
        col_s[pos] = (int)(p & 0x00FFFFFFu);
    }
}

// ---------------- t0 = dis ⊙ emb0, bf16 ----------------
__global__ void k_concat_t0(const float* __restrict__ u, const float* __restrict__ it,
                            const int* __restrict__ deg, u16* __restrict__ emb) {
    int i = blockIdx.x * blockDim.x + threadIdx.x;   // ushort4 index (4 dims), 16/row
    const int NU4 = NUSERS * DIM / 4;
    const int NT4 = NN * DIM / 4;
    if (i >= NT4) return;
    int row = i >> 4;
    int d = deg[row];
    float sc = (d > 0) ? (1.0f / sqrtf((float)d)) : 0.0f;
    float4 v = (i < NU4) ? ((const float4*)u)[i] : ((const float4*)it)[i - NU4];
    ushort4 o;
    o.x = f2bf(sc * v.x); o.y = f2bf(sc * v.y);
    o.z = f2bf(sc * v.z); o.w = f2bf(sc * v.w);
    ((ushort4*)emb)[i] = o;
}

// mark rows needed for hop-2 output: query rows + their CSR neighbors
__global__ void k_mark(const int* __restrict__ uid, const int* __restrict__ iid,
                       const int* __restrict__ rs, const int* __restrict__ deg,
                       const int* __restrict__ col_s, unsigned char* __restrict__ m2) {
    int q = blockIdx.x * blockDim.x + threadIdx.x;
    if (q >= 2 * BQ) return;
    int r = (q < BQ) ? uid[q] : (NUSERS + iid[q - BQ]);
    m2[r] = 1;
    int s = rs[r], n = deg[r];
    for (int i = 0; i < n; ++i) m2[col_s[s + i]] = 1;
}

// ---------------- SpMM in t-space: one wave per row, pipelined, no weights ----------
// t_{k+1}[r] = (1/deg[r]) * sum_{c in N(r)} t_k[c]
__global__ void k_spmm8(const int* __restrict__ rs, const int* __restrict__ deg,
                        const int* __restrict__ col_s, const u16* __restrict__ in,
                        u16* __restrict__ out, const unsigned char* __restrict__ mask) {
    int wid = (blockIdx.x * blockDim.x + threadIdx.x) >> 6;
    if (wid >= NN) return;
    if (mask && !mask[wid]) return;
    int lane = threadIdx.x & 63;
    int eslot = lane >> 3;
    int dg = lane & 7;
    int n = deg[wid];
    int start = rs[wid];
    int n8 = (n + 7) & ~7;
    const uint4* in4 = (const uint4*)in;
    float acc[8] = {0, 0, 0, 0, 0, 0, 0, 0};
    int i = eslot;
    if (i < n8) {
        int c0 = col_s[start + i];
        uint4 v0 = in4[(size_t)c0 * 8 + dg];
        for (i += 8; i < n8; i += 8) {
            int c1 = col_s[start + i];                 // prefetch next group
            uint4 v1 = in4[(size_t)c1 * 8 + dg];
            add8(acc, v0);                             // accumulate current
            v0 = v1;
        }
        add8(acc, v0);
    }
#pragma unroll
    for (int off = 8; off <= 32; off <<= 1)
#pragma unroll
        for (int j = 0; j < 8; ++j)
            acc[j] += __shfl_xor(acc[j], off, 64);
    if (eslot == 0) {
        float s = (n > 0) ? (1.0f / (float)n) : 0.0f;  // dis[r]^2
        u32 p0 = (u32)f2bf(acc[0] * s) | ((u32)f2bf(acc[1] * s) << 16);
        u32 p1 = (u32)f2bf(acc[2] * s) | ((u32)f2bf(acc[3] * s) << 16);
        u32 p2 = (u32)f2bf(acc[4] * s) | ((u32)f2bf(acc[5] * s) << 16);
        u32 p3 = (u32)f2bf(acc[6] * s) | ((u32)f2bf(acc[7] * s) << 16);
        ((uint4*)out)[(size_t)wid * 8 + dg] = make_uint4(p0, p1, p2, p3);
    }
}

// hop-3 fused: one wave per query slot; out = (out + dis[r]*sum t2[c]) * 0.25
__global__ void k_spmm_out(const int* __restrict__ rs, const int* __restrict__ deg,
                           const int* __restrict__ col_s, const u16* __restrict__ in,
                           const int* __restrict__ uid, const int* __restrict__ iid,
                           float* __restrict__ out) {
    int q = (blockIdx.x * blockDim.x + threadIdx.x) >> 6;
    if (q >= 2 * BQ) return;
    int lane = threadIdx.x & 63;
    int eslot = lane >> 3;
    int dg = lane & 7;
    int b, r, off;
    if (q < BQ) { b = q; r = uid[q]; off = 0; }
    else { b = q - BQ; r = NUSERS + iid[q - BQ]; off = DIM; }
    int n = deg[r];
    int start = rs[r];
    int n8 = (n + 7) & ~7;
    const uint4* in4 = (const uint4*)in;
    float acc[8] = {0, 0, 0, 0, 0, 0, 0, 0};
    int i = eslot;
    if (i < n8) {
        int c0 = col_s[start + i];
        uint4 v0 = in4[(size_t)c0 * 8 + dg];
        for (i += 8; i < n8; i += 8) {
            int c1 = col_s[start + i];
            uint4 v1 = in4[(size_t)c1 * 8 + dg];
            add8(acc, v0);
            v0 = v1;
        }
        add8(acc, v0);
    }
#pragma unroll
    for (int off2 = 8; off2 <= 32; off2 <<= 1)
#pragma unroll
        for (int j = 0; j < 8; ++j)
            acc[j] += __shfl_xor(acc[j], off2, 64);
    if (eslot == 0) {
        float dr = (n > 0) ? (1.0f / sqrtf((float)n)) : 0.0f;   // dis[r]
        float* o = out + (size_t)b * (2 * DIM) + off + dg * 8;
#pragma unroll
        for (int j = 0; j < 8; ++j)
            o[j] = (o[j] + dr * acc[j]) * 0.25f;
    }
}

// ---------------- output gathers ----------------

__global__ void k_gather_init(const int* __restrict__ uid, const int* __restrict__ iid,
                              const float* __restrict__ u, const float* __restrict__ it,
                              float* __restrict__ out) {
    int t = blockIdx.x * blockDim.x + threadIdx.x;
    if (t >= BQ * DIM) return;
    int b = t >> 6;
    int d = t & 63;
    out[b * (2 * DIM) + d]       = u[(size_t)uid[b] * DIM + d];
    out[b * (2 * DIM) + DIM + d] = it[(size_t)iid[b] * DIM + d];
}

// out += sqrt(deg[r]) * t_k[r]   (emb_k = rdis ⊙ t_k)
__global__ void k_gather_add(const int* __restrict__ uid, const int* __restrict__ iid,
                             const int* __restrict__ deg, const u16* __restrict__ emb,
                             float* __restrict__ out) {
    int t = blockIdx.x * blockDim.x + threadIdx.x;
    if (t >= BQ * DIM) return;
    int b = t >> 6;
    int d = t & 63;
    int ru = uid[b];
    int ri = NUSERS + iid[b];
    int du = deg[ru], di = deg[ri];
    float su = (du > 0) ? sqrtf((float)du) : 0.0f;
    float si = (di > 0) ? sqrtf((float)di) : 0.0f;
    int ou = b * (2 * DIM) + d;
    int oi = ou + DIM;
    out[ou] = out[ou] + su * bf2f(emb[(size_t)ru * DIM + d]);
    out[oi] = out[oi] + si * bf2f(emb[(size_t)ri * DIM + d]);
}

// ---------------- launch ----------------

extern "C" void kernel_launch(void* const* d_in, const int* in_sizes, int n_in,
                              void* d_out, int out_size, void* d_ws, size_t ws_size,
                              hipStream_t stream) {
    const float* users_emb = (const float*)d_in[0];
    const float* items_emb = (const float*)d_in[1];
    const int*   edge_row  = (const int*)d_in[2];
    const int*   edge_col  = (const int*)d_in[3];
    const int*   user_id   = (const int*)d_in[4];
    const int*   item_ids  = (const int*)d_in[5];
    float* out = (float*)d_out;

    char* ws = (char*)d_ws;
    // byte layout (ends ~90.3 MB):
    int*   deg_i   = (int*)  (ws + 0);          // 600 KB
    int*   rs      = (int*)  (ws + 655360);     // 600 KB
    int*   bin_cur = (int*)  (ws + 1310720);    // 2.4 KB
    unsigned char* m2 = (unsigned char*)(ws + 1400000);  // 150 KB (NN+1 used)
    int*   col_s   = (int*)  (ws + 4194304);    // 586*9216*4 = 21.6 MB
    u32*   pairs   = (u32*)  (ws + 29360128);   // 21.6 MB
    u16*   emb_a   = (u16*)  (ws + 54525952);   // (NN+1)*64*2 = 19.2 MB
    u16*   emb_b   = (u16*)  (ws + 75497472);   // 19.2 MB

    // init cursors + m2 + sentinel rows
    k_init<<<147, 256, 0, stream>>>(bin_cur, (u32*)m2, emb_a, emb_b);

    // binned CSR build (derives deg/rs in pass B; pads rows to x8 with sentinel)
    k_binA<<<(NE + EPB - 1) / EPB, 256, 0, stream>>>(edge_row, edge_col, bin_cur, pairs, NE);
    k_binB<<<NBIN, 256, 0, stream>>>(pairs, bin_cur, col_s, rs, deg_i);

    // t0 table (bf16, dis-folded)
    k_concat_t0<<<(NN * DIM / 4 + 255) / 256, 256, 0, stream>>>(users_emb, items_emb,
                                                                deg_i, emb_a);

    // layer-0 contribution (fp32 sources)
    k_gather_init<<<(BQ * DIM + 255) / 256, 256, 0, stream>>>(user_id, item_ids,
                                                              users_emb, items_emb, out);

    // mark rows whose hop-2 output is read
    k_mark<<<(2 * BQ + 255) / 256, 256, 0, stream>>>(user_id, item_ids, rs, deg_i, col_s, m2);

    const int spmm_blocks = (NN + 3) / 4;
    // hop 1: full
    k_spmm8<<<spmm_blocks, 256, 0, stream>>>(rs, deg_i, col_s, emb_a, emb_b,
                                             (const unsigned char*)nullptr);
    k_gather_add<<<(BQ * DIM + 255) / 256, 256, 0, stream>>>(user_id, item_ids, deg_i,
                                                             emb_b, out);
    // hop 2: masked
    k_spmm8<<<spmm_blocks, 256, 0, stream>>>(rs, deg_i, col_s, emb_b, emb_a, m2);
    k_gather_add<<<(BQ * DIM + 255) / 256, 256, 0, stream>>>(user_id, item_ids, deg_i,
                                                             emb_a, out);
    // hop 3: fused into output, fp32 accumulate, final /4
    k_spmm_out<<<(2 * BQ + 3) / 4, 256, 0, stream>>>(rs, deg_i, col_s, emb_a,
                                                     user_id, item_ids, out);
}

// Round 7
// 369.066 us; speedup vs baseline: 7.6531x; 1.0178x over previous
//
#include <hip/hip_runtime.h>

#define NUSERS 100000
#define NITEMS 50000
#define NN (NUSERS + NITEMS)      // 150000
#define NE 4000000
#define DIM 64
#define BQ 4096
#define NBIN ((NN + 255) >> 8)    // 586 bins of 256 rows
#define BINCAP 9216               // fixed slots/bin; mean w/ pads 7851, sigma ~90
#define EPB 4096                  // edges per block in pass A

typedef unsigned short u16;
typedef unsigned int u32;

__device__ __forceinline__ float bf2f(u16 u) {
    return __uint_as_float(((unsigned)u) << 16);
}
__device__ __forceinline__ u16 f2bf(float f) {
    unsigned x = __float_as_uint(f);
    return (u16)((x + 0x7FFFu + ((x >> 16) & 1u)) >> 16);   // RNE
}
// unpack uint4 (8 bf16) and accumulate (pure adds — weights folded into t-space)
__device__ __forceinline__ void add8(float* acc, uint4 u) {
    acc[0] += __uint_as_float(u.x << 16);
    acc[1] += __uint_as_float(u.x & 0xffff0000u);
    acc[2] += __uint_as_float(u.y << 16);
    acc[3] += __uint_as_float(u.y & 0xffff0000u);
    acc[4] += __uint_as_float(u.z << 16);
    acc[5] += __uint_as_float(u.z & 0xffff0000u);
    acc[6] += __uint_as_float(u.w << 16);
    acc[7] += __uint_as_float(u.w & 0xffff0000u);
}

// Shared row-sum core: cols preloaded in c_all (lane l holds col_s[start+l]),
// 4-deep gather batches. G = n8/8 groups (wave-uniform). acc[8] per lane.
__device__ __forceinline__ void rowsum_core(int start, int n8, int c_all,
                                            const int* __restrict__ col_s,
                                            const uint4* __restrict__ in4,
                                            int eslot, int dg, float* acc) {
    int G = n8 >> 3;
    if (G <= 8) {
        int cg[8];
#pragma unroll
        for (int g = 0; g < 8; ++g)
            cg[g] = (g < G) ? __shfl(c_all, (g << 3) + eslot, 64) : 0;
        int g = 0;
        while (g + 4 <= G) {
            uint4 v0 = in4[(size_t)cg[g]     * 8 + dg];
            uint4 v1 = in4[(size_t)cg[g + 1] * 8 + dg];
            uint4 v2 = in4[(size_t)cg[g + 2] * 8 + dg];
            uint4 v3 = in4[(size_t)cg[g + 3] * 8 + dg];
            add8(acc, v0); add8(acc, v1); add8(acc, v2); add8(acc, v3);
            g += 4;
        }
        if (g + 2 <= G) {
            uint4 v0 = in4[(size_t)cg[g]     * 8 + dg];
            uint4 v1 = in4[(size_t)cg[g + 1] * 8 + dg];
            add8(acc, v0); add8(acc, v1);
            g += 2;
        }
        if (g < G) {
            uint4 v0 = in4[(size_t)cg[g] * 8 + dg];
            add8(acc, v0);
        }
    } else {
        // fallback (deg > 64): plain pipelined loop over col_s
        int i = eslot;
        int c0 = col_s[start + i];
        uint4 v0 = in4[(size_t)c0 * 8 + dg];
        for (i += 8; i < n8; i += 8) {
            int c1 = col_s[start + i];
            uint4 v1 = in4[(size_t)c1 * 8 + dg];
            add8(acc, v0);
            v0 = v1;
        }
        add8(acc, v0);
    }
}

// ---------------- init: bin cursors, m2 mask, sentinel rows ----------------
__global__ void k_init(int* __restrict__ bin_cur, u32* __restrict__ m2w,
                       u16* __restrict__ ea, u16* __restrict__ eb) {
    int t = blockIdx.x * blockDim.x + threadIdx.x;
    if (t < NBIN) bin_cur[t] = t * BINCAP;
    if (t < 37504) m2w[t] = 0;                 // zero 150016 bytes of m2
    if (t < 32) {                              // zero sentinel row NN in both tables
        ((u32*)(ea + (size_t)NN * DIM))[t] = 0;
        ((u32*)(eb + (size_t)NN * DIM))[t] = 0;
    }
}

// ---------------- Pass A: bin edges, dense chunk-append ----------------
// Packed u32: (row&255)<<24 | col  (col < 150000 < 2^24)
__global__ void k_binA(const int* __restrict__ row, const int* __restrict__ col,
                       int* __restrict__ bin_cur, u32* __restrict__ pairs, int E) {
    __shared__ int hist[NBIN];
    __shared__ int cbase[NBIN];
    int t = threadIdx.x;
    for (int b = t; b < NBIN; b += 256) hist[b] = 0;
    __syncthreads();
    int base = blockIdx.x * EPB;
    int r[16], c[16];
#pragma unroll
    for (int i = 0; i < 16; ++i) {
        int e = base + i * 256 + t;
        if (e < E) {
            r[i] = row[e];
            c[i] = col[e];
            atomicAdd(&hist[r[i] >> 8], 1);
        } else {
            r[i] = -1;
        }
    }
    __syncthreads();
    for (int b = t; b < NBIN; b += 256) {
        int h = hist[b];
        cbase[b] = (h > 0) ? atomicAdd(&bin_cur[b], h) : 0;
    }
    __syncthreads();
#pragma unroll
    for (int i = 0; i < 16; ++i) {
        if (r[i] >= 0) {
            int b = r[i] >> 8;
            int off = atomicSub(&hist[b], 1) - 1;
            pairs[(size_t)cbase[b] + off] = ((u32)(r[i] & 255) << 24) | (u32)c[i];
        }
    }
}

// ---------------- Pass B: per-bin row sort; derives rs/deg; pads to 8 ----------------
__global__ void k_binB(const u32* __restrict__ pairs, const int* __restrict__ bin_cur,
                       int* __restrict__ col_s, int* __restrict__ rs,
                       int* __restrict__ deg) {
    __shared__ int cnt[256];
    __shared__ int pscan[256];
    __shared__ int cur[256];
    int b = blockIdx.x;
    int t = threadIdx.x;
    int base = b * BINCAP;
    int end = bin_cur[b];
    cnt[t] = 0;
    __syncthreads();
    for (int i = base + t; i < end; i += 256)
        atomicAdd(&cnt[pairs[i] >> 24], 1);
    __syncthreads();
    int v = cnt[t];
    int pv = (v + 7) & ~7;                    // row segment padded to multiple of 8
    pscan[t] = pv;
    __syncthreads();
    for (int off = 1; off < 256; off <<= 1) {
        int x = (t >= off) ? pscan[t - off] : 0;
        __syncthreads();
        pscan[t] += x;
        __syncthreads();
    }
    int rowstart = base + pscan[t] - pv;
    int r = (b << 8) + t;
    if (r < NN) {
        rs[r] = rowstart;
        deg[r] = v;
    }
    cur[t] = rowstart;
    for (int i = v; i < pv; ++i) col_s[rowstart + i] = NN;   // sentinel pads
    __syncthreads();
    for (int i = base + t; i < end; i += 256) {
        u32 p = pairs[i];
        int pos = atomicAdd(&cur[p >> 24], 1);
        col_s[pos] = (int)(p & 0x00FFFFFFu);
    }
}

// ---------------- t0 = dis ⊙ emb0, bf16 ----------------
__global__ void k_concat_t0(const float* __restrict__ u, const float* __restrict__ it,
                            const int* __restrict__ deg, u16* __restrict__ emb) {
    int i = blockIdx.x * blockDim.x + threadIdx.x;   // ushort4 index (4 dims), 16/row
    const int NU4 = NUSERS * DIM / 4;
    const int NT4 = NN * DIM / 4;
    if (i >= NT4) return;
    int row = i >> 4;
    int d = deg[row];
    float sc = (d > 0) ? (1.0f / sqrtf((float)d)) : 0.0f;
    float4 v = (i < NU4) ? ((const float4*)u)[i] : ((const float4*)it)[i - NU4];
    ushort4 o;
    o.x = f2bf(sc * v.x); o.y = f2bf(sc * v.y);
    o.z = f2bf(sc * v.z); o.w = f2bf(sc * v.w);
    ((ushort4*)emb)[i] = o;
}

// mark rows needed for hop-2 output: query rows + their CSR neighbors
__global__ void k_mark(const int* __restrict__ uid, const int* __restrict__ iid,
                       const int* __restrict__ rs, const int* __restrict__ deg,
                       const int* __restrict__ col_s, unsigned char* __restrict__ m2) {
    int q = blockIdx.x * blockDim.x + threadIdx.x;
    if (q >= 2 * BQ) return;
    int r = (q < BQ) ? uid[q] : (NUSERS + iid[q - BQ]);
    m2[r] = 1;
    int s = rs[r], n = deg[r];
    for (int i = 0; i < n; ++i) m2[col_s[s + i]] = 1;
}

// ---------------- SpMM in t-space: one wave per row ----------------
// t_{k+1}[r] = (1/deg[r]) * sum_{c in N(r)} t_k[c]
__global__ void k_spmm8(const int* __restrict__ rs, const int* __restrict__ deg,
                        const int* __restrict__ col_s, const u16* __restrict__ in,
                        u16* __restrict__ out, const unsigned char* __restrict__ mask) {
    int wid = (blockIdx.x * blockDim.x + threadIdx.x) >> 6;
    if (wid >= NN) return;
    if (mask && !mask[wid]) return;
    int lane = threadIdx.x & 63;
    int eslot = lane >> 3;
    int dg = lane & 7;
    int n = deg[wid];
    int start = rs[wid];
    int n8 = (n + 7) & ~7;
    int c_all = col_s[start + lane];           // preload up to 64 cols
    const uint4* in4 = (const uint4*)in;
    float acc[8] = {0, 0, 0, 0, 0, 0, 0, 0};
    if (n8 > 0)
        rowsum_core(start, n8, c_all, col_s, in4, eslot, dg, acc);
#pragma unroll
    for (int off = 8; off <= 32; off <<= 1)
#pragma unroll
        for (int j = 0; j < 8; ++j)
            acc[j] += __shfl_xor(acc[j], off, 64);
    if (eslot == 0) {
        float s = (n > 0) ? (1.0f / (float)n) : 0.0f;  // dis[r]^2
        u32 p0 = (u32)f2bf(acc[0] * s) | ((u32)f2bf(acc[1] * s) << 16);
        u32 p1 = (u32)f2bf(acc[2] * s) | ((u32)f2bf(acc[3] * s) << 16);
        u32 p2 = (u32)f2bf(acc[4] * s) | ((u32)f2bf(acc[5] * s) << 16);
        u32 p3 = (u32)f2bf(acc[6] * s) | ((u32)f2bf(acc[7] * s) << 16);
        ((uint4*)out)[(size_t)wid * 8 + dg] = make_uint4(p0, p1, p2, p3);
    }
}

// hop-3 fused: one wave per query slot; out = (out + dis[r]*sum t2[c]) * 0.25
__global__ void k_spmm_out(const int* __restrict__ rs, const int* __restrict__ deg,
                           const int* __restrict__ col_s, const u16* __restrict__ in,
                           const int* __restrict__ uid, const int* __restrict__ iid,
                           float* __restrict__ out) {
    int q = (blockIdx.x * blockDim.x + threadIdx.x) >> 6;
    if (q >= 2 * BQ) return;
    int lane = threadIdx.x & 63;
    int eslot = lane >> 3;
    int dg = lane & 7;
    int b, r, off;
    if (q < BQ) { b = q; r = uid[q]; off = 0; }
    else { b = q - BQ; r = NUSERS + iid[q - BQ]; off = DIM; }
    int n = deg[r];
    int start = rs[r];
    int n8 = (n + 7) & ~7;
    int c_all = col_s[start + lane];
    const uint4* in4 = (const uint4*)in;
    float acc[8] = {0, 0, 0, 0, 0, 0, 0, 0};
    if (n8 > 0)
        rowsum_core(start, n8, c_all, col_s, in4, eslot, dg, acc);
#pragma unroll
    for (int off2 = 8; off2 <= 32; off2 <<= 1)
#pragma unroll
        for (int j = 0; j < 8; ++j)
            acc[j] += __shfl_xor(acc[j], off2, 64);
    if (eslot == 0) {
        float dr = (n > 0) ? (1.0f / sqrtf((float)n)) : 0.0f;   // dis[r]
        float* o = out + (size_t)b * (2 * DIM) + off + dg * 8;
#pragma unroll
        for (int j = 0; j < 8; ++j)
            o[j] = (o[j] + dr * acc[j]) * 0.25f;
    }
}

// ---------------- output gathers ----------------

__global__ void k_gather_init(const int* __restrict__ uid, const int* __restrict__ iid,
                              const float* __restrict__ u, const float* __restrict__ it,
                              float* __restrict__ out) {
    int t = blockIdx.x * blockDim.x + threadIdx.x;
    if (t >= BQ * DIM) return;
    int b = t >> 6;
    int d = t & 63;
    out[b * (2 * DIM) + d]       = u[(size_t)uid[b] * DIM + d];
    out[b * (2 * DIM) + DIM + d] = it[(size_t)iid[b] * DIM + d];
}

// out += sqrt(deg[r]) * t_k[r]   (emb_k = rdis ⊙ t_k)
__global__ void k_gather_add(const int* __restrict__ uid, const int* __restrict__ iid,
                             const int* __restrict__ deg, const u16* __restrict__ emb,
                             float* __restrict__ out) {
    int t = blockIdx.x * blockDim.x + threadIdx.x;
    if (t >= BQ * DIM) return;
    int b = t >> 6;
    int d = t & 63;
    int ru = uid[b];
    int ri = NUSERS + iid[b];
    int du = deg[ru], di = deg[ri];
    float su = (du > 0) ? sqrtf((float)du) : 0.0f;
    float si = (di > 0) ? sqrtf((float)di) : 0.0f;
    int ou = b * (2 * DIM) + d;
    int oi = ou + DIM;
    out[ou] = out[ou] + su * bf2f(emb[(size_t)ru * DIM + d]);
    out[oi] = out[oi] + si * bf2f(emb[(size_t)ri * DIM + d]);
}

// ---------------- launch ----------------

extern "C" void kernel_launch(void* const* d_in, const int* in_sizes, int n_in,
                              void* d_out, int out_size, void* d_ws, size_t ws_size,
                              hipStream_t stream) {
    const float* users_emb = (const float*)d_in[0];
    const float* items_emb = (const float*)d_in[1];
    const int*   edge_row  = (const int*)d_in[2];
    const int*   edge_col  = (const int*)d_in[3];
    const int*   user_id   = (const int*)d_in[4];
    const int*   item_ids  = (const int*)d_in[5];
    float* out = (float*)d_out;

    char* ws = (char*)d_ws;
    // byte layout (ends ~90.3 MB):
    int*   deg_i   = (int*)  (ws + 0);          // 600 KB
    int*   rs      = (int*)  (ws + 655360);     // 600 KB
    int*   bin_cur = (int*)  (ws + 1310720);    // 2.4 KB
    unsigned char* m2 = (unsigned char*)(ws + 1400000);  // 150 KB
    int*   col_s   = (int*)  (ws + 4194304);    // 586*9216*4 = 21.6 MB
    u32*   pairs   = (u32*)  (ws + 29360128);   // 21.6 MB
    u16*   emb_a   = (u16*)  (ws + 54525952);   // (NN+1)*64*2 = 19.2 MB
    u16*   emb_b   = (u16*)  (ws + 75497472);   // 19.2 MB

    // init cursors + m2 + sentinel rows
    k_init<<<147, 256, 0, stream>>>(bin_cur, (u32*)m2, emb_a, emb_b);

    // binned CSR build (derives deg/rs in pass B; pads rows to x8 with sentinel)
    k_binA<<<(NE + EPB - 1) / EPB, 256, 0, stream>>>(edge_row, edge_col, bin_cur, pairs, NE);
    k_binB<<<NBIN, 256, 0, stream>>>(pairs, bin_cur, col_s, rs, deg_i);

    // t0 table (bf16, dis-folded)
    k_concat_t0<<<(NN * DIM / 4 + 255) / 256, 256, 0, stream>>>(users_emb, items_emb,
                                                                deg_i, emb_a);

    // layer-0 contribution (fp32 sources)
    k_gather_init<<<(BQ * DIM + 255) / 256, 256, 0, stream>>>(user_id, item_ids,
                                                              users_emb, items_emb, out);

    // mark rows whose hop-2 output is read
    k_mark<<<(2 * BQ + 255) / 256, 256, 0, stream>>>(user_id, item_ids, rs, deg_i, col_s, m2);

    const int spmm_blocks = (NN + 3) / 4;
    // hop 1: full
    k_spmm8<<<spmm_blocks, 256, 0, stream>>>(rs, deg_i, col_s, emb_a, emb_b,
                                             (const unsigned char*)nullptr);
    k_gather_add<<<(BQ * DIM + 255) / 256, 256, 0, stream>>>(user_id, item_ids, deg_i,
                                                             emb_b, out);
    // hop 2: masked
    k_spmm8<<<spmm_blocks, 256, 0, stream>>>(rs, deg_i, col_s, emb_b, emb_a, m2);
    k_gather_add<<<(BQ * DIM + 255) / 256, 256, 0, stream>>>(user_id, item_ids, deg_i,
                                                             emb_a, out);
    // hop 3: fused into output, fp32 accumulate, final /4
    k_spmm_out<<<(2 * BQ + 3) / 4, 256, 0, stream>>>(rs, deg_i, col_s, emb_a,
                                                     user_id, item_ids, out);
}

// Round 8
// 356.107 us; speedup vs baseline: 7.9316x; 1.0364x over previous
//
#include <hip/hip_runtime.h>
#include <hip/hip_bf16.h>

#define NUSERS 100000
#define NITEMS 50000
#define NN (NUSERS + NITEMS)      // 150000
#define NE 4000000
#define DIM 64
#define BQ 4096
#define NBIN ((NN + 255) >> 8)    // 586 bins of 256 rows
#define BINCAP 9216               // fixed slots/bin; mean w/ pads 7851, sigma ~90
#define EPB 4096                  // edges per block in pass A

typedef unsigned short u16;
typedef unsigned int u32;
typedef float v2f __attribute__((ext_vector_type(2)));

__device__ __forceinline__ float bf2f(u16 u) {
    return __uint_as_float(((unsigned)u) << 16);
}
__device__ __forceinline__ u16 f2bf(float f) {
    unsigned x = __float_as_uint(f);
    return (u16)((x + 0x7FFFu + ((x >> 16) & 1u)) >> 16);   // RNE
}
// unpack uint4 (8 bf16) into 4 packed-f32 accumulates (v_pk_add_f32)
__device__ __forceinline__ void add8p(v2f* acc2, uint4 u) {
    acc2[0] += (v2f){__uint_as_float(u.x << 16), __uint_as_float(u.x & 0xffff0000u)};
    acc2[1] += (v2f){__uint_as_float(u.y << 16), __uint_as_float(u.y & 0xffff0000u)};
    acc2[2] += (v2f){__uint_as_float(u.z << 16), __uint_as_float(u.z & 0xffff0000u)};
    acc2[3] += (v2f){__uint_as_float(u.w << 16), __uint_as_float(u.w & 0xffff0000u)};
}
// 32-bit voffset + SGPR base load: offset = c*128 + dgoff, fits 25 bits
__device__ __forceinline__ uint4 ld_row(const char* __restrict__ base, int c, int dgoff) {
    u32 off = ((u32)c << 7) + (u32)dgoff;
    return *(const uint4*)(base + off);
}

// Shared row-sum core: cols preloaded in c_all (lane l holds col_s[start+l]),
// all G<=8 gathers issued before any add (max MLP). G wave-uniform.
__device__ __forceinline__ void rowsum_core(int start, int n8, int c_all,
                                            const int* __restrict__ col_s,
                                            const char* __restrict__ inb,
                                            int eslot, int dgoff, v2f* acc2) {
    int G = n8 >> 3;
    if (G <= 8) {
        int cg[8];
#pragma unroll
        for (int g = 0; g < 8; ++g)
            cg[g] = __shfl(c_all, (g << 3) + eslot, 64);
        uint4 v[8];
#pragma unroll
        for (int g = 0; g < 8; ++g)
            if (g < G) v[g] = ld_row(inb, cg[g], dgoff);
#pragma unroll
        for (int g = 0; g < 8; ++g)
            if (g < G) add8p(acc2, v[g]);
    } else {
        // fallback (deg > 64): pipelined loop over col_s
        int i = eslot;
        int c0 = col_s[start + i];
        uint4 v0 = ld_row(inb, c0, dgoff);
        for (i += 8; i < n8; i += 8) {
            int c1 = col_s[start + i];
            uint4 v1 = ld_row(inb, c1, dgoff);
            add8p(acc2, v0);
            v0 = v1;
        }
        add8p(acc2, v0);
    }
}

// wave-wide reduction over the 8 edge slots (pairs stay packed)
__device__ __forceinline__ void reduce_acc(v2f* acc2) {
#pragma unroll
    for (int off = 8; off <= 32; off <<= 1)
#pragma unroll
        for (int j = 0; j < 4; ++j) {
            v2f o;
            o.x = __shfl_xor(acc2[j].x, off, 64);
            o.y = __shfl_xor(acc2[j].y, off, 64);
            acc2[j] += o;
        }
}

// ---------------- init: bin cursors, m2 mask, sentinel rows ----------------
__global__ void k_init(int* __restrict__ bin_cur, u32* __restrict__ m2w,
                       u16* __restrict__ ea, u16* __restrict__ eb) {
    int t = blockIdx.x * blockDim.x + threadIdx.x;
    if (t < NBIN) bin_cur[t] = t * BINCAP;
    if (t < 37504) m2w[t] = 0;                 // zero 150016 bytes of m2
    if (t < 32) {                              // zero sentinel row NN in both tables
        ((u32*)(ea + (size_t)NN * DIM))[t] = 0;
        ((u32*)(eb + (size_t)NN * DIM))[t] = 0;
    }
}

// ---------------- Pass A: bin edges, dense chunk-append ----------------
// Packed u32: (row&255)<<24 | col  (col < 150000 < 2^24)
__global__ void k_binA(const int* __restrict__ row, const int* __restrict__ col,
                       int* __restrict__ bin_cur, u32* __restrict__ pairs, int E) {
    __shared__ int hist[NBIN];
    __shared__ int cbase[NBIN];
    int t = threadIdx.x;
    for (int b = t; b < NBIN; b += 256) hist[b] = 0;
    __syncthreads();
    int base = blockIdx.x * EPB;
    int r[16], c[16];
#pragma unroll
    for (int i = 0; i < 16; ++i) {
        int e = base + i * 256 + t;
        if (e < E) {
            r[i] = row[e];
            c[i] = col[e];
            atomicAdd(&hist[r[i] >> 8], 1);
        } else {
            r[i] = -1;
        }
    }
    __syncthreads();
    for (int b = t; b < NBIN; b += 256) {
        int h = hist[b];
        cbase[b] = (h > 0) ? atomicAdd(&bin_cur[b], h) : 0;
    }
    __syncthreads();
#pragma unroll
    for (int i = 0; i < 16; ++i) {
        if (r[i] >= 0) {
            int b = r[i] >> 8;
            int off = atomicSub(&hist[b], 1) - 1;
            pairs[(size_t)cbase[b] + off] = ((u32)(r[i] & 255) << 24) | (u32)c[i];
        }
    }
}

// ---------------- Pass B: per-bin row sort; derives rs/deg; pads to 8 ----------------
__global__ void k_binB(const u32* __restrict__ pairs, const int* __restrict__ bin_cur,
                       int* __restrict__ col_s, int* __restrict__ rs,
                       int* __restrict__ deg) {
    __shared__ int cnt[256];
    __shared__ int pscan[256];
    __shared__ int cur[256];
    int b = blockIdx.x;
    int t = threadIdx.x;
    int base = b * BINCAP;
    int end = bin_cur[b];
    cnt[t] = 0;
    __syncthreads();
    for (int i = base + t; i < end; i += 256)
        atomicAdd(&cnt[pairs[i] >> 24], 1);
    __syncthreads();
    int v = cnt[t];
    int pv = (v + 7) & ~7;                    // row segment padded to multiple of 8
    pscan[t] = pv;
    __syncthreads();
    for (int off = 1; off < 256; off <<= 1) {
        int x = (t >= off) ? pscan[t - off] : 0;
        __syncthreads();
        pscan[t] += x;
        __syncthreads();
    }
    int rowstart = base + pscan[t] - pv;
    int r = (b << 8) + t;
    if (r < NN) {
        rs[r] = rowstart;
        deg[r] = v;
    }
    cur[t] = rowstart;
    for (int i = v; i < pv; ++i) col_s[rowstart + i] = NN;   // sentinel pads
    __syncthreads();
    for (int i = base + t; i < end; i += 256) {
        u32 p = pairs[i];
        int pos = atomicAdd(&cur[p >> 24], 1);
        col_s[pos] = (int)(p & 0x00FFFFFFu);
    }
}

// ---------------- t0 = dis ⊙ emb0, bf16 ----------------
__global__ void k_concat_t0(const float* __restrict__ u, const float* __restrict__ it,
                            const int* __restrict__ deg, u16* __restrict__ emb) {
    int i = blockIdx.x * blockDim.x + threadIdx.x;   // ushort4 index (4 dims), 16/row
    const int NU4 = NUSERS * DIM / 4;
    const int NT4 = NN * DIM / 4;
    if (i >= NT4) return;
    int row = i >> 4;
    int d = deg[row];
    float sc = (d > 0) ? (1.0f / sqrtf((float)d)) : 0.0f;
    float4 v = (i < NU4) ? ((const float4*)u)[i] : ((const float4*)it)[i - NU4];
    ushort4 o;
    o.x = f2bf(sc * v.x); o.y = f2bf(sc * v.y);
    o.z = f2bf(sc * v.z); o.w = f2bf(sc * v.w);
    ((ushort4*)emb)[i] = o;
}

// mark rows needed for hop-2 output: query rows + their CSR neighbors
__global__ void k_mark(const int* __restrict__ uid, const int* __restrict__ iid,
                       const int* __restrict__ rs, const int* __restrict__ deg,
                       const int* __restrict__ col_s, unsigned char* __restrict__ m2) {
    int q = blockIdx.x * blockDim.x + threadIdx.x;
    if (q >= 2 * BQ) return;
    int r = (q < BQ) ? uid[q] : (NUSERS + iid[q - BQ]);
    m2[r] = 1;
    int s = rs[r], n = deg[r];
    for (int i = 0; i < n; ++i) m2[col_s[s + i]] = 1;
}

// ---------------- SpMM in t-space: one wave per row ----------------
// t_{k+1}[r] = (1/deg[r]) * sum_{c in N(r)} t_k[c]
__global__ void k_spmm8(const int* __restrict__ rs, const int* __restrict__ deg,
                        const int* __restrict__ col_s, const u16* __restrict__ in,
                        u16* __restrict__ out, const unsigned char* __restrict__ mask) {
    int wid = (blockIdx.x * blockDim.x + threadIdx.x) >> 6;
    if (wid >= NN) return;
    if (mask && !mask[wid]) return;
    int lane = threadIdx.x & 63;
    int eslot = lane >> 3;
    int dg = lane & 7;
    int dgoff = dg << 4;
    int n = deg[wid];
    int start = rs[wid];
    int n8 = (n + 7) & ~7;
    int c_all = col_s[start + lane];           // preload up to 64 cols
    const char* inb = (const char*)in;
    v2f acc2[4] = {(v2f)0.f, (v2f)0.f, (v2f)0.f, (v2f)0.f};
    if (n8 > 0)
        rowsum_core(start, n8, c_all, col_s, inb, eslot, dgoff, acc2);
    reduce_acc(acc2);
    if (eslot == 0) {
        float s = (n > 0) ? (1.0f / (float)n) : 0.0f;  // dis[r]^2
        v2f vs = {s, s};
        u32 p[4];
#pragma unroll
        for (int j = 0; j < 4; ++j) {
            v2f r = acc2[j] * vs;
            __hip_bfloat162 h = __float22bfloat162_rn(make_float2(r.x, r.y));
            p[j] = *(u32*)&h;
        }
        ((uint4*)out)[(size_t)wid * 8 + dg] = make_uint4(p[0], p[1], p[2], p[3]);
    }
}

// hop-3 fused: one wave per query slot; out = (out + dis[r]*sum t2[c]) * 0.25
__global__ void k_spmm_out(const int* __restrict__ rs, const int* __restrict__ deg,
                           const int* __restrict__ col_s, const u16* __restrict__ in,
                           const int* __restrict__ uid, const int* __restrict__ iid,
                           float* __restrict__ out) {
    int q = (blockIdx.x * blockDim.x + threadIdx.x) >> 6;
    if (q >= 2 * BQ) return;
    int lane = threadIdx.x & 63;
    int eslot = lane >> 3;
    int dg = lane & 7;
    int dgoff = dg << 4;
    int b, r, off;
    if (q < BQ) { b = q; r = uid[q]; off = 0; }
    else { b = q - BQ; r = NUSERS + iid[q - BQ]; off = DIM; }
    int n = deg[r];
    int start = rs[r];
    int n8 = (n + 7) & ~7;
    int c_all = col_s[start + lane];
    const char* inb = (const char*)in;
    v2f acc2[4] = {(v2f)0.f, (v2f)0.f, (v2f)0.f, (v2f)0.f};
    if (n8 > 0)
        rowsum_core(start, n8, c_all, col_s, inb, eslot, dgoff, acc2);
    reduce_acc(acc2);
    if (eslot == 0) {
        float dr = (n > 0) ? (1.0f / sqrtf((float)n)) : 0.0f;   // dis[r]
        float* o = out + (size_t)b * (2 * DIM) + off + dg * 8;
#pragma unroll
        for (int j = 0; j < 4; ++j) {
            o[2 * j]     = (o[2 * j]     + dr * acc2[j].x) * 0.25f;
            o[2 * j + 1] = (o[2 * j + 1] + dr * acc2[j].y) * 0.25f;
        }
    }
}

// ---------------- output gathers ----------------

__global__ void k_gather_init(const int* __restrict__ uid, const int* __restrict__ iid,
                              const float* __restrict__ u, const float* __restrict__ it,
                              float* __restrict__ out) {
    int t = blockIdx.x * blockDim.x + threadIdx.x;
    if (t >= BQ * DIM) return;
    int b = t >> 6;
    int d = t & 63;
    out[b * (2 * DIM) + d]       = u[(size_t)uid[b] * DIM + d];
    out[b * (2 * DIM) + DIM + d] = it[(size_t)iid[b] * DIM + d];
}

// out += sqrt(deg[r]) * t_k[r]   (emb_k = rdis ⊙ t_k)
__global__ void k_gather_add(const int* __restrict__ uid, const int* __restrict__ iid,
                             const int* __restrict__ deg, const u16* __restrict__ emb,
                             float* __restrict__ out) {
    int t = blockIdx.x * blockDim.x + threadIdx.x;
    if (t >= BQ * DIM) return;
    int b = t >> 6;
    int d = t & 63;
    int ru = uid[b];
    int ri = NUSERS + iid[b];
    int du = deg[ru], di = deg[ri];
    float su = (du > 0) ? sqrtf((float)du) : 0.0f;
    float si = (di > 0) ? sqrtf((float)di) : 0.0f;
    int ou = b * (2 * DIM) + d;
    int oi = ou + DIM;
    out[ou] = out[ou] + su * bf2f(emb[(size_t)ru * DIM + d]);
    out[oi] = out[oi] + si * bf2f(emb[(size_t)ri * DIM + d]);
}

// ---------------- launch ----------------

extern "C" void kernel_launch(void* const* d_in, const int* in_sizes, int n_in,
                              void* d_out, int out_size, void* d_ws, size_t ws_size,
                              hipStream_t stream) {
    const float* users_emb = (const float*)d_in[0];
    const float* items_emb = (const float*)d_in[1];
    const int*   edge_row  = (const int*)d_in[2];
    const int*   edge_col  = (const int*)d_in[3];
    const int*   user_id   = (const int*)d_in[4];
    const int*   item_ids  = (const int*)d_in[5];
    float* out = (float*)d_out;

    char* ws = (char*)d_ws;
    // byte layout (ends ~90.3 MB):
    int*   deg_i   = (int*)  (ws + 0);          // 600 KB
    int*   rs      = (int*)  (ws + 655360);     // 600 KB
    int*   bin_cur = (int*)  (ws + 1310720);    // 2.4 KB
    unsigned char* m2 = (unsigned char*)(ws + 1400000);  // 150 KB
    int*   col_s   = (int*)  (ws + 4194304);    // 586*9216*4 = 21.6 MB
    u32*   pairs   = (u32*)  (ws + 29360128);   // 21.6 MB
    u16*   emb_a   = (u16*)  (ws + 54525952);   // (NN+1)*64*2 = 19.2 MB
    u16*   emb_b   = (u16*)  (ws + 75497472);   // 19.2 MB

    // init cursors + m2 + sentinel rows
    k_init<<<147, 256, 0, stream>>>(bin_cur, (u32*)m2, emb_a, emb_b);

    // binned CSR build (derives deg/rs in pass B; pads rows to x8 with sentinel)
    k_binA<<<(NE + EPB - 1) / EPB, 256, 0, stream>>>(edge_row, edge_col, bin_cur, pairs, NE);
    k_binB<<<NBIN, 256, 0, stream>>>(pairs, bin_cur, col_s, rs, deg_i);

    // t0 table (bf16, dis-folded)
    k_concat_t0<<<(NN * DIM / 4 + 255) / 256, 256, 0, stream>>>(users_emb, items_emb,
                                                                deg_i, emb_a);

    // layer-0 contribution (fp32 sources)
    k_gather_init<<<(BQ * DIM + 255) / 256, 256, 0, stream>>>(user_id, item_ids,
                                                              users_emb, items_emb, out);

    // mark rows whose hop-2 output is read
    k_mark<<<(2 * BQ + 255) / 256, 256, 0, stream>>>(user_id, item_ids, rs, deg_i, col_s, m2);

    const int spmm_blocks = (NN + 3) / 4;
    // hop 1: full
    k_spmm8<<<spmm_blocks, 256, 0, stream>>>(rs, deg_i, col_s, emb_a, emb_b,
                                             (const unsigned char*)nullptr);
    k_gather_add<<<(BQ * DIM + 255) / 256, 256, 0, stream>>>(user_id, item_ids, deg_i,
                                                             emb_b, out);
    // hop 2: masked
    k_spmm8<<<spmm_blocks, 256, 0, stream>>>(rs, deg_i, col_s, emb_b, emb_a, m2);
    k_gather_add<<<(BQ * DIM + 255) / 256, 256, 0, stream>>>(user_id, item_ids, deg_i,
                                                             emb_a, out);
    // hop 3: fused into output, fp32 accumulate, final /4
    k_spmm_out<<<(2 * BQ + 3) / 4, 256, 0, stream>>>(rs, deg_i, col_s, emb_a,
                                                     user_id, item_ids, out);
}